// Round 5
// baseline (1736.870 us; speedup 1.0000x reference)
//
#include <hip/hip_runtime.h>
#include <hip/hip_bf16.h>

typedef __bf16 bf16;
typedef unsigned short u16;
typedef bf16 bf16x8 __attribute__((ext_vector_type(8)));
typedef bf16 bf16x4 __attribute__((ext_vector_type(4)));
typedef float f32x4 __attribute__((ext_vector_type(4)));

constexpr int NN = 30000;
constexpr int NE = 600000;
constexpr int D  = 128;

__device__ inline f32x4 mfma16(bf16x8 a, bf16x8 b, f32x4 c) {
    return __builtin_amdgcn_mfma_f32_16x16x32_bf16(a, b, c, 0, 0, 0);
}
__device__ inline bf16x8 ld8(const bf16* p) {
    return *reinterpret_cast<const bf16x8*>(p);
}
__device__ inline bf16x8 ld8nt(const bf16* p) {
    return __builtin_nontemporal_load(reinterpret_cast<const bf16x8*>(p));
}
__device__ inline bf16x4 ld4nt(const bf16* p) {
    return __builtin_nontemporal_load(reinterpret_cast<const bf16x4*>(p));
}
__device__ inline bf16x8 cvt8(const float* p) {
    float4 v0 = reinterpret_cast<const float4*>(p)[0];
    float4 v1 = reinterpret_cast<const float4*>(p)[1];
    bf16x8 r;
    r[0] = (bf16)v0.x; r[1] = (bf16)v0.y; r[2] = (bf16)v0.z; r[3] = (bf16)v0.w;
    r[4] = (bf16)v1.x; r[5] = (bf16)v1.y; r[6] = (bf16)v1.z; r[7] = (bf16)v1.w;
    return r;
}
__device__ inline int swz512(int row, int byteInRow) {
    return row * 512 + (byteInRow ^ ((row & 15) << 4));
}

// ---------------------------------------------------------------- prep
struct TMat { const float* src; bf16* dst; int K; int Nc; };
struct TPack { TMat m[12]; };

__global__ void transpose_cast_kernel(TPack p) {
    TMat mm = p.m[blockIdx.x];
    int total = mm.K * mm.Nc;
    for (int idx = blockIdx.y * blockDim.x + threadIdx.x; idx < total;
         idx += gridDim.y * blockDim.x) {
        int c = idx / mm.K;
        int k = idx - c * mm.K;
        mm.dst[idx] = (bf16)mm.src[k * mm.Nc + c];
    }
}

__global__ void fuse_kernel(const float* __restrict__ W_el2,
                            const float* __restrict__ W_ero,
                            const float* __restrict__ W_logit,
                            const float* __restrict__ b_el2,
                            const float* __restrict__ b_ero,
                            const float* __restrict__ b_logit,
                            bf16* __restrict__ W2eroT, bf16* __restrict__ W2lgT,
                            float* __restrict__ b2ero, float* __restrict__ b2lg) {
    int k = blockIdx.x;
    int c = threadIdx.x;
    if (c >= 144) return;
    if (k < 256) {
        if (c < 128) {
            float s = 0.f;
            for (int j = 0; j < 128; ++j) s += W_el2[k * 128 + j] * W_ero[j * 128 + c];
            W2eroT[c * 256 + k] = (bf16)s;
        } else {
            int cc = c - 128;
            float s = 0.f;
            if (cc < 2) for (int j = 0; j < 128; ++j) s += W_el2[k * 128 + j] * W_logit[j * 2 + cc];
            W2lgT[cc * 256 + k] = (bf16)s;
        }
    } else {
        if (c < 128) {
            float s = b_ero[c];
            for (int j = 0; j < 128; ++j) s += 2.f * b_el2[j] * W_ero[j * 128 + c];
            b2ero[c] = s;
        } else if (c < 130) {
            int cc = c - 128;
            float s = b_logit[cc];
            for (int j = 0; j < 128; ++j) s += 2.f * b_el2[j] * W_logit[j * 2 + cc];
            b2lg[cc] = s;
        }
    }
}

// ---------------------------------------------------------------- sort (counting sort by dst)
__global__ void hist_kernel(const int* __restrict__ dst, int* __restrict__ counts) {
    int e = blockIdx.x * blockDim.x + threadIdx.x;
    if (e < NE) atomicAdd(counts + dst[e], 1);
}

// single-pass block scan: 1024 threads x 30 entries each
__global__ void scan_kernel(const int* __restrict__ counts, int* __restrict__ offsets,
                            int* __restrict__ cursor) {
    __shared__ int part[1024];
    const int t = threadIdx.x;
    const int base = t * 30;
    int local[30];
    int s = 0;
#pragma unroll
    for (int i = 0; i < 30; ++i) {
        int idx = base + i;
        int v = (idx < NN) ? counts[idx] : 0;
        local[i] = s;
        s += v;
    }
    part[t] = s;
    __syncthreads();
    for (int off = 1; off < 1024; off <<= 1) {
        int x = (t >= off) ? part[t - off] : 0;
        __syncthreads();
        part[t] += x;
        __syncthreads();
    }
    int chunkExcl = (t == 0) ? 0 : part[t - 1];
#pragma unroll
    for (int i = 0; i < 30; ++i) {
        int idx = base + i;
        if (idx < NN) {
            int excl = chunkExcl + local[i];
            offsets[idx] = excl;
            cursor[idx] = excl;
        }
    }
    if (t == 0) offsets[NN] = NE;
}

__global__ void scatter_kernel(const int* __restrict__ src, const int* __restrict__ dst,
                               int* __restrict__ cursor, int* __restrict__ perm,
                               u16* __restrict__ srcS, u16* __restrict__ dstS) {
    int e = blockIdx.x * blockDim.x + threadIdx.x;
    if (e < NE) {
        int d = dst[e];
        int p = atomicAdd(cursor + d, 1);
        perm[p] = e;
        srcS[p] = (u16)src[e];
        dstS[p] = (u16)d;
    }
}

// ---------------------------------------------------------------- node-level GEMMs
template<bool IN_BF16>
__global__ void __launch_bounds__(256, 4)
node_pre_kernel(const float* __restrict__ inF, const bf16* __restrict__ inB,
                const bf16* __restrict__ WT,       // [512][128]
                const float* __restrict__ bias0,
                bf16* __restrict__ O1, bf16* __restrict__ O2) {
    const int half = blockIdx.y;
    const int r0 = blockIdx.x * 64;
    const int t = threadIdx.x, wv = t >> 6, l = t & 63, lr = l & 15, qk = l >> 4;
    int row[4];
#pragma unroll
    for (int m = 0; m < 4; ++m) { int r = r0 + m * 16 + lr; row[m] = r < NN ? r : NN - 1; }
    int coln[4];
#pragma unroll
    for (int n = 0; n < 4; ++n) coln[n] = wv * 64 + n * 16 + lr;
    f32x4 acc[4][4];
#pragma unroll
    for (int m = 0; m < 4; ++m)
#pragma unroll
        for (int n = 0; n < 4; ++n) acc[m][n] = 0.f;
#pragma unroll
    for (int ks = 0; ks < 4; ++ks) {
        const int kg = ks * 32 + qk * 8;
        bf16x8 a[4], b[4];
#pragma unroll
        for (int m = 0; m < 4; ++m)
            a[m] = IN_BF16 ? ld8(inB + row[m] * D + kg) : cvt8(inF + row[m] * D + kg);
#pragma unroll
        for (int n = 0; n < 4; ++n) b[n] = ld8(WT + (half * 256 + coln[n]) * 128 + kg);
#pragma unroll
        for (int m = 0; m < 4; ++m)
#pragma unroll
            for (int n = 0; n < 4; ++n) acc[m][n] = mfma16(a[m], b[n], acc[m][n]);
    }
    bf16* O = half ? O2 : O1;
#pragma unroll
    for (int n = 0; n < 4; ++n) {
        float bia = (half == 0 && bias0) ? bias0[coln[n]] : 0.f;
#pragma unroll
        for (int m = 0; m < 4; ++m)
#pragma unroll
            for (int j = 0; j < 4; ++j) {
                int gr = r0 + m * 16 + qk * 4 + j;
                if (gr < NN) O[gr * 256 + coln[n]] = (bf16)(acc[m][n][j] + bia);
            }
    }
}

// S[r][c] += h1[r] @ WtopT[c]
template<bool HBF>
__global__ void __launch_bounds__(256, 4)
s2_update_kernel(const void* __restrict__ h1, const bf16* __restrict__ WtopT,
                 bf16* __restrict__ S) {
    const int r0 = blockIdx.x * 64;
    const int t = threadIdx.x, wv = t >> 6, l = t & 63, lr = l & 15, qk = l >> 4;
    int row[4];
#pragma unroll
    for (int m = 0; m < 4; ++m) { int r = r0 + m * 16 + lr; row[m] = r < NN ? r : NN - 1; }
    int coln[4];
#pragma unroll
    for (int n = 0; n < 4; ++n) coln[n] = wv * 64 + n * 16 + lr;
    f32x4 acc[4][4];
#pragma unroll
    for (int m = 0; m < 4; ++m)
#pragma unroll
        for (int n = 0; n < 4; ++n) acc[m][n] = 0.f;
#pragma unroll
    for (int ks = 0; ks < 4; ++ks) {
        const int kg = ks * 32 + qk * 8;
        bf16x8 a[4], b[4];
#pragma unroll
        for (int m = 0; m < 4; ++m) {
            if constexpr (HBF) a[m] = ld8((const bf16*)h1 + row[m] * D + kg);
            else               a[m] = cvt8((const float*)h1 + row[m] * D + kg);
        }
#pragma unroll
        for (int n = 0; n < 4; ++n) b[n] = ld8(WtopT + coln[n] * 128 + kg);
#pragma unroll
        for (int m = 0; m < 4; ++m)
#pragma unroll
            for (int n = 0; n < 4; ++n) acc[m][n] = mfma16(a[m], b[n], acc[m][n]);
    }
#pragma unroll
    for (int n = 0; n < 4; ++n)
#pragma unroll
        for (int m = 0; m < 4; ++m)
#pragma unroll
            for (int j = 0; j < 4; ++j) {
                int gr = r0 + m * 16 + qk * 4 + j;
                if (gr < NN) {
                    int idx = gr * 256 + coln[n];
                    S[idx] = (bf16)((float)S[idx] + acc[m][n][j]);
                }
            }
}

// ---------------------------------------------------------------- segment sum (one wave per dst)
__global__ void __launch_bounds__(256, 8)
seg_sum_kernel(const bf16* __restrict__ S, const bf16* __restrict__ Bm,
               const int* __restrict__ offsets, const u16* __restrict__ srcS,
               bf16* __restrict__ T) {
    const int gw = (blockIdx.x * blockDim.x + threadIdx.x) >> 6;
    if (gw >= NN) return;
    const int l = threadIdx.x & 63;
    const int beg = offsets[gw], end = offsets[gw + 1];
    bf16x4 bv = *reinterpret_cast<const bf16x4*>(Bm + (size_t)gw * 256 + l * 4);
    const float b0 = (float)bv[0], b1 = (float)bv[1], b2 = (float)bv[2], b3 = (float)bv[3];
    float t0 = 0.f, t1 = 0.f, t2 = 0.f, t3 = 0.f;
    int i = beg;
    for (; i + 2 <= end; i += 2) {
        int s0 = srcS[i];
        int s1 = srcS[i + 1];
        bf16x4 a0 = ld4nt(S + (size_t)s0 * 256 + l * 4);
        bf16x4 a1 = ld4nt(S + (size_t)s1 * 256 + l * 4);
        float v;
        v = (float)a0[0] + b0; t0 += v > 0.f ? v : 0.f;
        v = (float)a0[1] + b1; t1 += v > 0.f ? v : 0.f;
        v = (float)a0[2] + b2; t2 += v > 0.f ? v : 0.f;
        v = (float)a0[3] + b3; t3 += v > 0.f ? v : 0.f;
        v = (float)a1[0] + b0; t0 += v > 0.f ? v : 0.f;
        v = (float)a1[1] + b1; t1 += v > 0.f ? v : 0.f;
        v = (float)a1[2] + b2; t2 += v > 0.f ? v : 0.f;
        v = (float)a1[3] + b3; t3 += v > 0.f ? v : 0.f;
    }
    if (i < end) {
        int s0 = srcS[i];
        bf16x4 a0 = ld4nt(S + (size_t)s0 * 256 + l * 4);
        float v;
        v = (float)a0[0] + b0; t0 += v > 0.f ? v : 0.f;
        v = (float)a0[1] + b1; t1 += v > 0.f ? v : 0.f;
        v = (float)a0[2] + b2; t2 += v > 0.f ? v : 0.f;
        v = (float)a0[3] + b3; t3 += v > 0.f ? v : 0.f;
    }
    bf16x4 o;
    o[0] = (bf16)t0; o[1] = (bf16)t1; o[2] = (bf16)t2; o[3] = (bf16)t3;
    __builtin_nontemporal_store(o, reinterpret_cast<bf16x4*>(T + (size_t)gw * 256 + l * 4));
}

// h[r] = T[r] @ We2T + deg[r]*b_e2   (bf16 out)
__global__ void __launch_bounds__(256, 4)
h_gemm_kernel(const bf16* __restrict__ T, const bf16* __restrict__ We2T,
              const float* __restrict__ b_e2, const int* __restrict__ deg,
              bf16* __restrict__ h) {
    const int r0 = blockIdx.x * 64;
    const int t = threadIdx.x, wv = t >> 6, l = t & 63, lr = l & 15, qk = l >> 4;
    int row[4];
#pragma unroll
    for (int m = 0; m < 4; ++m) { int r = r0 + m * 16 + lr; row[m] = r < NN ? r : NN - 1; }
    int col2[2];
#pragma unroll
    for (int n = 0; n < 2; ++n) col2[n] = wv * 32 + n * 16 + lr;
    f32x4 acc[4][2];
#pragma unroll
    for (int m = 0; m < 4; ++m)
#pragma unroll
        for (int n = 0; n < 2; ++n) acc[m][n] = 0.f;
#pragma unroll
    for (int ks = 0; ks < 8; ++ks) {
        const int kg = ks * 32 + qk * 8;
        bf16x8 a[4], b[2];
#pragma unroll
        for (int m = 0; m < 4; ++m) a[m] = ld8(T + (size_t)row[m] * 256 + kg);
#pragma unroll
        for (int n = 0; n < 2; ++n) b[n] = ld8(We2T + col2[n] * 256 + kg);
#pragma unroll
        for (int m = 0; m < 4; ++m)
#pragma unroll
            for (int n = 0; n < 2; ++n) acc[m][n] = mfma16(a[m], b[n], acc[m][n]);
    }
#pragma unroll
    for (int n = 0; n < 2; ++n) {
        float bw = b_e2[col2[n]];
#pragma unroll
        for (int m = 0; m < 4; ++m)
#pragma unroll
            for (int j = 0; j < 4; ++j) {
                int gr = r0 + m * 16 + qk * 4 + j;
                if (gr < NN)
                    h[(size_t)gr * D + col2[n]] = (bf16)(acc[m][n][j] + (float)deg[gr] * bw);
            }
    }
}

// ---------------------------------------------------------------- node MLP (nf2 only)
template<bool HBF>
__global__ void __launch_bounds__(256, 2)
node_mlp_kernel(const float* __restrict__ node_feat,
                const void* __restrict__ h2,
                const bf16* __restrict__ Wn1T,
                const bf16* __restrict__ Wn2T,
                const float* __restrict__ b_n1,
                const float* __restrict__ b_n2,
                bf16* __restrict__ nf2_bf) {
    __shared__ __align__(16) char sH[64 * 512];
    const int t = threadIdx.x, wv = t >> 6, l = t & 63, lr = l & 15, qk = l >> 4;
    const int r0 = blockIdx.x * 64;
    int row[4];
#pragma unroll
    for (int m = 0; m < 4; ++m) { int r = r0 + m * 16 + lr; row[m] = r < NN ? r : NN - 1; }
    int coln[4];
#pragma unroll
    for (int n = 0; n < 4; ++n) coln[n] = wv * 64 + n * 16 + lr;
    f32x4 acc[4][4];
#pragma unroll
    for (int m = 0; m < 4; ++m)
#pragma unroll
        for (int n = 0; n < 4; ++n) acc[m][n] = 0.f;
#pragma unroll
    for (int ks = 0; ks < 4; ++ks) {
        const int kg = ks * 32 + qk * 8;
        bf16x8 a[4], b[4];
#pragma unroll
        for (int m = 0; m < 4; ++m) a[m] = cvt8(node_feat + (size_t)row[m] * D + kg);
#pragma unroll
        for (int n = 0; n < 4; ++n) b[n] = ld8(Wn1T + coln[n] * 256 + kg);
#pragma unroll
        for (int m = 0; m < 4; ++m)
#pragma unroll
            for (int n = 0; n < 4; ++n) acc[m][n] = mfma16(a[m], b[n], acc[m][n]);
#pragma unroll
        for (int m = 0; m < 4; ++m) {
            if constexpr (HBF) a[m] = ld8((const bf16*)h2 + (size_t)row[m] * D + kg);
            else               a[m] = cvt8((const float*)h2 + (size_t)row[m] * D + kg);
        }
#pragma unroll
        for (int n = 0; n < 4; ++n) b[n] = ld8(Wn1T + coln[n] * 256 + 128 + kg);
#pragma unroll
        for (int m = 0; m < 4; ++m)
#pragma unroll
            for (int n = 0; n < 4; ++n) acc[m][n] = mfma16(a[m], b[n], acc[m][n]);
    }
#pragma unroll
    for (int n = 0; n < 4; ++n) {
        float bia = b_n1[coln[n]];
#pragma unroll
        for (int m = 0; m < 4; ++m)
#pragma unroll
            for (int j = 0; j < 4; ++j) {
                int r = m * 16 + qk * 4 + j;
                float v = acc[m][n][j] + bia;
                v = v > 0.f ? v : 0.f;
                *reinterpret_cast<bf16*>(sH + swz512(r, coln[n] * 2)) = (bf16)v;
            }
    }
    __syncthreads();
    int col2[2];
#pragma unroll
    for (int n = 0; n < 2; ++n) col2[n] = wv * 32 + n * 16 + lr;
    f32x4 acc2[4][2];
#pragma unroll
    for (int m = 0; m < 4; ++m)
#pragma unroll
        for (int n = 0; n < 2; ++n) acc2[m][n] = 0.f;
#pragma unroll
    for (int ks = 0; ks < 8; ++ks) {
        const int k0 = ks * 32 + qk * 8;
        bf16x8 a[4], b[2];
#pragma unroll
        for (int m = 0; m < 4; ++m)
            a[m] = *reinterpret_cast<const bf16x8*>(sH + swz512(m * 16 + lr, k0 * 2));
#pragma unroll
        for (int n = 0; n < 2; ++n) b[n] = ld8(Wn2T + col2[n] * 256 + k0);
#pragma unroll
        for (int m = 0; m < 4; ++m)
#pragma unroll
            for (int n = 0; n < 2; ++n) acc2[m][n] = mfma16(a[m], b[n], acc2[m][n]);
    }
#pragma unroll
    for (int n = 0; n < 2; ++n) {
        float bia = b_n2[col2[n]];
#pragma unroll
        for (int m = 0; m < 4; ++m)
#pragma unroll
            for (int j = 0; j < 4; ++j) {
                int gr = r0 + m * 16 + qk * 4 + j;
                if (gr < NN) nf2_bf[(size_t)gr * D + col2[n]] = (bf16)(acc2[m][n][j] + bia);
            }
    }
}

// ---------------------------------------------------------------- edge logits (dst-sorted)
// r3 epilogue (direct scattered stores) + NT stores + NT s-side loads + 8 blocks/CU
__global__ void __launch_bounds__(256, 8)
edge_logit_sorted(const bf16* __restrict__ U, const bf16* __restrict__ V,
                  const int* __restrict__ perm, const u16* __restrict__ srcS,
                  const u16* __restrict__ dstS,
                  const bf16* __restrict__ W2eroT, const bf16* __restrict__ W2lgT,
                  const float* __restrict__ b2ero, const float* __restrict__ b2lg,
                  float* __restrict__ e_ro, float* __restrict__ e_lg) {
    __shared__ int s_e[128];
    __shared__ int s_s[128];
    __shared__ int s_d[128];
    const int t = threadIdx.x, wv = t >> 6, l = t & 63, lr = l & 15, qk = l >> 4;
    const int p0 = blockIdx.x * 128;
    if (t < 128) {
        int p = min(p0 + t, NE - 1);
        s_e[t] = perm[p];
        s_s[t] = (int)srcS[p];
        s_d[t] = (int)dstS[p];
    }
    __syncthreads();

    int is[2], id[2];
#pragma unroll
    for (int m = 0; m < 2; ++m) {
        int el = wv * 32 + m * 16 + lr;
        is[m] = s_s[el];
        id[m] = s_d[el];
    }
    f32x4 aro[2][8];
    f32x4 alg[2];
#pragma unroll
    for (int m = 0; m < 2; ++m) {
        alg[m] = 0.f;
#pragma unroll
        for (int n = 0; n < 8; ++n) aro[m][n] = 0.f;
    }
#pragma unroll
    for (int ks = 0; ks < 8; ++ks) {
        const int kg = ks * 32 + qk * 8;
        bf16x8 a[2];
#pragma unroll
        for (int m = 0; m < 2; ++m) {
            bf16x8 us = ld8nt(U + (size_t)is[m] * 256 + kg);   // random, no reuse -> NT
            bf16x8 vs = ld8nt(V + (size_t)is[m] * 256 + kg);
            bf16x8 ud = ld8(U + (size_t)id[m] * 256 + kg);     // block-local reuse -> cached
            bf16x8 vd = ld8(V + (size_t)id[m] * 256 + kg);
#pragma unroll
            for (int i = 0; i < 8; ++i) {
                float f1 = (float)us[i] + (float)vd[i]; f1 = f1 > 0.f ? f1 : 0.f;
                float f2 = (float)ud[i] + (float)vs[i]; f2 = f2 > 0.f ? f2 : 0.f;
                a[m][i] = (bf16)(f1 + f2);
            }
        }
#pragma unroll
        for (int n = 0; n < 8; ++n) {
            bf16x8 b = ld8(W2eroT + (n * 16 + lr) * 256 + kg);
#pragma unroll
            for (int m = 0; m < 2; ++m) aro[m][n] = mfma16(a[m], b, aro[m][n]);
        }
        bf16x8 blg = ld8(W2lgT + lr * 256 + kg);
#pragma unroll
        for (int m = 0; m < 2; ++m) alg[m] = mfma16(a[m], blg, alg[m]);
    }
#pragma unroll
    for (int n = 0; n < 8; ++n) {
        int col = n * 16 + lr;
        float bia = b2ero[col];
#pragma unroll
        for (int m = 0; m < 2; ++m)
#pragma unroll
            for (int j = 0; j < 4; ++j) {
                int el = wv * 32 + m * 16 + qk * 4 + j;
                __builtin_nontemporal_store(aro[m][n][j] + bia,
                                            e_ro + (size_t)s_e[el] * D + col);
            }
    }
    if (lr < 2) {
        float bia = b2lg[lr];
#pragma unroll
        for (int m = 0; m < 2; ++m)
#pragma unroll
            for (int j = 0; j < 4; ++j) {
                int el = wv * 32 + m * 16 + qk * 4 + j;
                __builtin_nontemporal_store(alg[m][j] + bia,
                                            e_lg + (size_t)s_e[el] * 2 + lr);
            }
    }
}

// ---------------------------------------------------------------- fallback kernels (round-2 path)
__global__ void __launch_bounds__(256, 4)
edge_msg_kernel(const bf16* __restrict__ S, const bf16* __restrict__ Bm,
                const int* __restrict__ src, const int* __restrict__ dst,
                const bf16* __restrict__ We2T,
                const float* __restrict__ b_e2,
                float* __restrict__ h_out) {
    __shared__ int s_src[128];
    __shared__ int s_dst[128];
    const int t = threadIdx.x, wv = t >> 6, l = t & 63, lr = l & 15, qk = l >> 4;
    const int e0 = blockIdx.x * 128;
    if (t < 128)      s_src[t] = src[min(e0 + t, NE - 1)];
    else              s_dst[t - 128] = dst[min(e0 + t - 128, NE - 1)];
    __syncthreads();
    const bf16* pS[2];
    const bf16* pB[2];
#pragma unroll
    for (int m = 0; m < 2; ++m) {
        int el = wv * 32 + m * 16 + lr;
        pS[m] = S + s_src[el] * 256;
        pB[m] = Bm + s_dst[el] * 256;
    }
    f32x4 acc[2][8];
#pragma unroll
    for (int m = 0; m < 2; ++m)
#pragma unroll
        for (int n = 0; n < 8; ++n) acc[m][n] = 0.f;
#pragma unroll
    for (int ks = 0; ks < 8; ++ks) {
        const int kg = ks * 32 + qk * 8;
        bf16x8 a[2];
#pragma unroll
        for (int m = 0; m < 2; ++m) {
            bf16x8 sa = ld8(pS[m] + kg);
            bf16x8 sb = ld8(pB[m] + kg);
#pragma unroll
            for (int i = 0; i < 8; ++i) {
                float f = (float)sa[i] + (float)sb[i];
                a[m][i] = (bf16)(f > 0.f ? f : 0.f);
            }
        }
#pragma unroll
        for (int n = 0; n < 8; ++n) {
            bf16x8 b = ld8(We2T + (n * 16 + lr) * 256 + kg);
#pragma unroll
            for (int m = 0; m < 2; ++m) acc[m][n] = mfma16(a[m], b, acc[m][n]);
        }
    }
#pragma unroll
    for (int n = 0; n < 8; ++n) {
        int col = n * 16 + lr;
        float bia = b_e2[col];
#pragma unroll
        for (int m = 0; m < 2; ++m)
#pragma unroll
            for (int j = 0; j < 4; ++j) {
                int el = wv * 32 + m * 16 + qk * 4 + j;
                if (e0 + el < NE)
                    atomicAdd(h_out + s_dst[el] * D + col, acc[m][n][j] + bia);
            }
    }
}

__global__ void __launch_bounds__(256, 4)
edge_logit_fast(const bf16* __restrict__ U, const bf16* __restrict__ V,
                const int* __restrict__ src, const int* __restrict__ dst,
                const bf16* __restrict__ W2eroT,
                const bf16* __restrict__ W2lgT,
                const float* __restrict__ b2ero, const float* __restrict__ b2lg,
                float* __restrict__ e_ro, float* __restrict__ e_lg) {
    __shared__ int s_src[128];
    __shared__ int s_dst[128];
    const int t = threadIdx.x, wv = t >> 6, l = t & 63, lr = l & 15, qk = l >> 4;
    const int e0 = blockIdx.x * 128;
    if (t < 128)      s_src[t] = src[min(e0 + t, NE - 1)];
    else              s_dst[t - 128] = dst[min(e0 + t - 128, NE - 1)];
    __syncthreads();
    int is[2], id[2];
#pragma unroll
    for (int m = 0; m < 2; ++m) {
        int el = wv * 32 + m * 16 + lr;
        is[m] = s_src[el];
        id[m] = s_dst[el];
    }
    f32x4 aro[2][8];
    f32x4 alg[2];
#pragma unroll
    for (int m = 0; m < 2; ++m) {
        alg[m] = 0.f;
#pragma unroll
        for (int n = 0; n < 8; ++n) aro[m][n] = 0.f;
    }
#pragma unroll
    for (int ks = 0; ks < 8; ++ks) {
        const int kg = ks * 32 + qk * 8;
        bf16x8 a[2];
#pragma unroll
        for (int m = 0; m < 2; ++m) {
            bf16x8 us = ld8(U + is[m] * 256 + kg);
            bf16x8 vd = ld8(V + id[m] * 256 + kg);
            bf16x8 ud = ld8(U + id[m] * 256 + kg);
            bf16x8 vs = ld8(V + is[m] * 256 + kg);
#pragma unroll
            for (int i = 0; i < 8; ++i) {
                float f1 = (float)us[i] + (float)vd[i]; f1 = f1 > 0.f ? f1 : 0.f;
                float f2 = (float)ud[i] + (float)vs[i]; f2 = f2 > 0.f ? f2 : 0.f;
                a[m][i] = (bf16)(f1 + f2);
            }
        }
#pragma unroll
        for (int n = 0; n < 8; ++n) {
            bf16x8 b = ld8(W2eroT + (n * 16 + lr) * 256 + kg);
#pragma unroll
            for (int m = 0; m < 2; ++m) aro[m][n] = mfma16(a[m], b, aro[m][n]);
        }
        bf16x8 blg = ld8(W2lgT + lr * 256 + kg);
#pragma unroll
        for (int m = 0; m < 2; ++m) alg[m] = mfma16(a[m], blg, alg[m]);
    }
#pragma unroll
    for (int n = 0; n < 8; ++n) {
        int col = n * 16 + lr;
        float bia = b2ero[col];
#pragma unroll
        for (int m = 0; m < 2; ++m)
#pragma unroll
            for (int j = 0; j < 4; ++j) {
                int el = wv * 32 + m * 16 + qk * 4 + j;
                int e = e0 + el;
                if (e < NE) e_ro[e * D + col] = aro[m][n][j] + bia;
            }
    }
    if (lr < 2) {
        float bia = b2lg[lr];
#pragma unroll
        for (int m = 0; m < 2; ++m)
#pragma unroll
            for (int j = 0; j < 4; ++j) {
                int el = wv * 32 + m * 16 + qk * 4 + j;
                int e = e0 + el;
                if (e < NE) e_lg[e * 2 + lr] = alg[m][j] + bia;
            }
    }
}

// ---------------------------------------------------------------- n_out readout
__global__ void __launch_bounds__(256, 4)
nro_kernel(const bf16* __restrict__ nf2_bf, const bf16* __restrict__ WnroT,
           const float* __restrict__ b_nro, float* __restrict__ n_out) {
    const int r0 = blockIdx.x * 64;
    const int t = threadIdx.x, wv = t >> 6, l = t & 63, lr = l & 15, qk = l >> 4;
    int row[4];
#pragma unroll
    for (int m = 0; m < 4; ++m) { int r = r0 + m * 16 + lr; row[m] = r < NN ? r : NN - 1; }
    int col2[2];
#pragma unroll
    for (int n = 0; n < 2; ++n) col2[n] = wv * 32 + n * 16 + lr;
    f32x4 acc[4][2];
#pragma unroll
    for (int m = 0; m < 4; ++m)
#pragma unroll
        for (int n = 0; n < 2; ++n) acc[m][n] = 0.f;
#pragma unroll
    for (int ks = 0; ks < 4; ++ks) {
        const int kg = ks * 32 + qk * 8;
        bf16x8 a[4], b[2];
#pragma unroll
        for (int m = 0; m < 4; ++m) a[m] = ld8(nf2_bf + (size_t)row[m] * D + kg);
#pragma unroll
        for (int n = 0; n < 2; ++n) b[n] = ld8(WnroT + col2[n] * 128 + kg);
#pragma unroll
        for (int m = 0; m < 4; ++m)
#pragma unroll
            for (int n = 0; n < 2; ++n) acc[m][n] = mfma16(a[m], b[n], acc[m][n]);
    }
#pragma unroll
    for (int n = 0; n < 2; ++n) {
        float bia = b_nro[col2[n]];
#pragma unroll
        for (int m = 0; m < 4; ++m)
#pragma unroll
            for (int j = 0; j < 4; ++j) {
                int gr = r0 + m * 16 + qk * 4 + j;
                if (gr < NN) n_out[(size_t)gr * D + col2[n]] = acc[m][n][j] + bia;
            }
    }
}

// ---------------------------------------------------------------- launch
extern "C" void kernel_launch(void* const* d_in, const int* in_sizes, int n_in,
                              void* d_out, int out_size, void* d_ws, size_t ws_size,
                              hipStream_t stream) {
    const float* node_feat = (const float*)d_in[0];
    const int*   src   = (const int*)d_in[1];
    const int*   dst   = (const int*)d_in[2];
    const float* W_e1  = (const float*)d_in[3];
    const float* b_e1  = (const float*)d_in[4];
    const float* W_e2  = (const float*)d_in[5];
    const float* b_e2  = (const float*)d_in[6];
    const float* W_n1  = (const float*)d_in[7];
    const float* b_n1  = (const float*)d_in[8];
    const float* W_n2  = (const float*)d_in[9];
    const float* b_n2  = (const float*)d_in[10];
    const float* W_el1 = (const float*)d_in[11];
    const float* b_el1 = (const float*)d_in[12];
    const float* W_el2 = (const float*)d_in[13];
    const float* b_el2 = (const float*)d_in[14];
    const float* W_logit = (const float*)d_in[15];
    const float* b_logit = (const float*)d_in[16];
    const float* W_nro = (const float*)d_in[17];
    const float* b_nro = (const float*)d_in[18];
    const float* W_ero = (const float*)d_in[19];
    const float* b_ero = (const float*)d_in[20];

    char* ws = (char*)d_ws;
    bf16* wb = (bf16*)ws;
    bf16* WmbT   = wb;            // [512][128]
    bf16* WtopT  = wb + 65536;    // [256][128]
    bf16* We2T   = wb + 98304;    // [128][256]
    bf16* Wn1T   = wb + 131072;   // [256][256]
    bf16* Wn2T   = wb + 196608;   // [128][256]
    bf16* WuvT   = wb + 229376;   // [512][128]
    bf16* WnroT  = wb + 294912;   // [128][128]
    bf16* W2eroT = wb + 311296;   // [128][256]
    bf16* W2lgT  = wb + 344064;   // [16][256]
    float* fb    = (float*)(ws + 928000);
    float* b2ero = fb;
    float* b2lg  = fb + 128;

    float* out   = (float*)d_out;
    float* n_out = out;                 // NN*128 f32 (15.36 MB)
    float* e_ro  = out + 3840000;       // NE*128 f32 (307.2 MB)
    float* e_lg  = out + 80640000;      // NE*2 f32 (4.8 MB)

    TPack pk;
    pk.m[0]  = {W_e1 + 128 * 256, WmbT,              128, 256};
    pk.m[1]  = {W_e1 + 256 * 256, WmbT + 256 * 128,  128, 256};
    pk.m[2]  = {W_e1,             WtopT,             128, 256};
    pk.m[3]  = {W_e2,             We2T,              256, 128};
    pk.m[4]  = {W_n1,             Wn1T,              256, 256};
    pk.m[5]  = {W_n2,             Wn2T,              256, 128};
    pk.m[6]  = {W_el1,            WuvT,              128, 256};
    pk.m[7]  = {W_el1 + 128 * 256, WuvT + 256 * 128, 128, 256};
    pk.m[8]  = {W_nro,            WnroT,             128, 128};
    pk.m[9]  = {W_nro,            WnroT,             128, 128};
    pk.m[10] = {W_nro,            WnroT,             128, 128};
    pk.m[11] = {W_nro,            WnroT,             128, 128};

    const size_t NEED_NEW = 28888576;

    if (ws_size >= NEED_NEW) {
        // ---------------- dst-sorted CSR, atomic-free ----------------
        char* eb = (char*)e_ro;   // 307.2 MB of dead-until-logit space
        bf16* S    = (bf16*)(eb);
        bf16* Bm   = (bf16*)(eb + 15360000);
        bf16* T    = (bf16*)(eb + 30720000);
        bf16* h1   = (bf16*)(eb + 46080000);
        bf16* h2   = (bf16*)(eb + 53760000);
        int* counts  = (int*)(eb + 61440000);
        int* offsets = (int*)(eb + 61560000);
        int* cursor  = (int*)(eb + 61680004);
        bf16* U    = (bf16*)n_out;           // dead until nro (runs last)
        bf16* nf2_bf = (bf16*)(ws + 1048576);
        bf16* Vbuf   = (bf16*)(ws + 8728576);
        int*  perm   = (int*)(ws + 24088576);
        u16*  srcS   = (u16*)(ws + 26488576);
        u16*  dstS   = (u16*)(ws + 27688576);

        transpose_cast_kernel<<<dim3(12, 40), 256, 0, stream>>>(pk);
        fuse_kernel<<<257, 160, 0, stream>>>(W_el2, W_ero, W_logit, b_el2, b_ero, b_logit,
                                             W2eroT, W2lgT, b2ero, b2lg);
        hipMemsetAsync(counts, 0, NN * 4, stream);
        hist_kernel<<<(NE + 255) / 256, 256, 0, stream>>>(dst, counts);
        scan_kernel<<<1, 1024, 0, stream>>>(counts, offsets, cursor);
        scatter_kernel<<<(NE + 255) / 256, 256, 0, stream>>>(src, dst, cursor,
                                                             perm, srcS, dstS);
        node_pre_kernel<false><<<dim3(469, 2), 256, 0, stream>>>(
            node_feat, nullptr, WmbT, b_e1, S, Bm);
        seg_sum_kernel<<<7500, 256, 0, stream>>>(S, Bm, offsets, srcS, T);
        h_gemm_kernel<<<469, 256, 0, stream>>>(T, We2T, b_e2, counts, h1);
        s2_update_kernel<true><<<469, 256, 0, stream>>>(h1, WtopT, S);
        seg_sum_kernel<<<7500, 256, 0, stream>>>(S, Bm, offsets, srcS, T);
        h_gemm_kernel<<<469, 256, 0, stream>>>(T, We2T, b_e2, counts, h2);
        node_mlp_kernel<true><<<469, 256, 0, stream>>>(
            node_feat, h2, Wn1T, Wn2T, b_n1, b_n2, nf2_bf);
        node_pre_kernel<true><<<dim3(469, 2), 256, 0, stream>>>(
            nullptr, nf2_bf, WuvT, b_el1, U, Vbuf);
        edge_logit_sorted<<<4688, 256, 0, stream>>>(
            U, Vbuf, perm, srcS, dstS, W2eroT, W2lgT, b2ero, b2lg, e_ro, e_lg);
        nro_kernel<<<469, 256, 0, stream>>>(nf2_bf, WnroT, b_nro, n_out);
    } else {
        // ---------------- fallback: round-2 proven path ----------------
        bf16* nf2_bf = (bf16*)(ws + 1048576);
        bf16* Vbuf   = (bf16*)(ws + 9000000);
        float* h1f = n_out;
        bf16*  S   = (bf16*)e_ro;
        bf16*  Bm  = (bf16*)((char*)e_ro + 15360000);
        float* h2f = (float*)((char*)e_ro + 30720000);
        bf16*  U   = (bf16*)n_out;

        transpose_cast_kernel<<<dim3(12, 40), 256, 0, stream>>>(pk);
        fuse_kernel<<<257, 160, 0, stream>>>(W_el2, W_ero, W_logit, b_el2, b_ero, b_logit,
                                             W2eroT, W2lgT, b2ero, b2lg);
        hipMemsetAsync(h1f, 0, (size_t)NN * D * 4, stream);
        hipMemsetAsync(h2f, 0, (size_t)NN * D * 4, stream);
        node_pre_kernel<false><<<dim3(469, 2), 256, 0, stream>>>(
            node_feat, nullptr, WmbT, b_e1, S, Bm);
        edge_msg_kernel<<<4688, 256, 0, stream>>>(S, Bm, src, dst, We2T, b_e2, h1f);
        s2_update_kernel<false><<<469, 256, 0, stream>>>(h1f, WtopT, S);
        edge_msg_kernel<<<4688, 256, 0, stream>>>(S, Bm, src, dst, We2T, b_e2, h2f);
        node_mlp_kernel<false><<<469, 256, 0, stream>>>(
            node_feat, h2f, Wn1T, Wn2T, b_n1, b_n2, nf2_bf);
        node_pre_kernel<true><<<dim3(469, 2), 256, 0, stream>>>(
            nullptr, nf2_bf, WuvT, b_el1, U, Vbuf);
        edge_logit_fast<<<4688, 256, 0, stream>>>(
            U, Vbuf, src, dst, W2eroT, W2lgT, b2ero, b2lg, e_ro, e_lg);
        nro_kernel<<<469, 256, 0, stream>>>(nf2_bf, WnroT, b_nro, n_out);
    }
}

// Round 6
// 1673.706 us; speedup vs baseline: 1.0377x; 1.0377x over previous
//
#include <hip/hip_runtime.h>
#include <hip/hip_bf16.h>

typedef __bf16 bf16;
typedef unsigned short u16;
typedef bf16 bf16x8 __attribute__((ext_vector_type(8)));
typedef bf16 bf16x4 __attribute__((ext_vector_type(4)));
typedef float f32x4 __attribute__((ext_vector_type(4)));

constexpr int NN = 30000;
constexpr int NE = 600000;
constexpr int D  = 128;

__device__ inline f32x4 mfma16(bf16x8 a, bf16x8 b, f32x4 c) {
    return __builtin_amdgcn_mfma_f32_16x16x32_bf16(a, b, c, 0, 0, 0);
}
__device__ inline bf16x8 ld8(const bf16* p) {
    return *reinterpret_cast<const bf16x8*>(p);
}
__device__ inline bf16x8 cvt8(const float* p) {
    float4 v0 = reinterpret_cast<const float4*>(p)[0];
    float4 v1 = reinterpret_cast<const float4*>(p)[1];
    bf16x8 r;
    r[0] = (bf16)v0.x; r[1] = (bf16)v0.y; r[2] = (bf16)v0.z; r[3] = (bf16)v0.w;
    r[4] = (bf16)v1.x; r[5] = (bf16)v1.y; r[6] = (bf16)v1.z; r[7] = (bf16)v1.w;
    return r;
}
__device__ inline int swz512(int row, int byteInRow) {
    return row * 512 + (byteInRow ^ ((row & 15) << 4));
}

// ---------------------------------------------------------------- prep
struct TMat { const float* src; bf16* dst; int K; int Nc; };
struct TPack { TMat m[12]; };

__global__ void transpose_cast_kernel(TPack p) {
    TMat mm = p.m[blockIdx.x];
    int total = mm.K * mm.Nc;
    for (int idx = blockIdx.y * blockDim.x + threadIdx.x; idx < total;
         idx += gridDim.y * blockDim.x) {
        int c = idx / mm.K;
        int k = idx - c * mm.K;
        mm.dst[idx] = (bf16)mm.src[k * mm.Nc + c];
    }
}

__global__ void fuse_kernel(const float* __restrict__ W_el2,
                            const float* __restrict__ W_ero,
                            const float* __restrict__ W_logit,
                            const float* __restrict__ b_el2,
                            const float* __restrict__ b_ero,
                            const float* __restrict__ b_logit,
                            bf16* __restrict__ W2eroT, bf16* __restrict__ W2lgT,
                            float* __restrict__ b2ero, float* __restrict__ b2lg) {
    int k = blockIdx.x;
    int c = threadIdx.x;
    if (c >= 144) return;
    if (k < 256) {
        if (c < 128) {
            float s = 0.f;
            for (int j = 0; j < 128; ++j) s += W_el2[k * 128 + j] * W_ero[j * 128 + c];
            W2eroT[c * 256 + k] = (bf16)s;
        } else {
            int cc = c - 128;
            float s = 0.f;
            if (cc < 2) for (int j = 0; j < 128; ++j) s += W_el2[k * 128 + j] * W_logit[j * 2 + cc];
            W2lgT[cc * 256 + k] = (bf16)s;
        }
    } else {
        if (c < 128) {
            float s = b_ero[c];
            for (int j = 0; j < 128; ++j) s += 2.f * b_el2[j] * W_ero[j * 128 + c];
            b2ero[c] = s;
        } else if (c < 130) {
            int cc = c - 128;
            float s = b_logit[cc];
            for (int j = 0; j < 128; ++j) s += 2.f * b_el2[j] * W_logit[j * 2 + cc];
            b2lg[cc] = s;
        }
    }
}

// ---------------------------------------------------------------- sort (counting sort by dst)
__global__ void hist_kernel(const int* __restrict__ dst, int* __restrict__ counts) {
    int e = blockIdx.x * blockDim.x + threadIdx.x;
    if (e < NE) atomicAdd(counts + dst[e], 1);
}

// single-pass block scan: 1024 threads x 30 entries each
__global__ void scan_kernel(const int* __restrict__ counts, int* __restrict__ offsets,
                            int* __restrict__ cursor) {
    __shared__ int part[1024];
    const int t = threadIdx.x;
    const int base = t * 30;
    int local[30];
    int s = 0;
#pragma unroll
    for (int i = 0; i < 30; ++i) {
        int idx = base + i;
        int v = (idx < NN) ? counts[idx] : 0;
        local[i] = s;
        s += v;
    }
    part[t] = s;
    __syncthreads();
    for (int off = 1; off < 1024; off <<= 1) {
        int x = (t >= off) ? part[t - off] : 0;
        __syncthreads();
        part[t] += x;
        __syncthreads();
    }
    int chunkExcl = (t == 0) ? 0 : part[t - 1];
#pragma unroll
    for (int i = 0; i < 30; ++i) {
        int idx = base + i;
        if (idx < NN) {
            int excl = chunkExcl + local[i];
            offsets[idx] = excl;
            cursor[idx] = excl;
        }
    }
    if (t == 0) offsets[NN] = NE;
}

__global__ void scatter_kernel(const int* __restrict__ src, const int* __restrict__ dst,
                               int* __restrict__ cursor, int* __restrict__ perm,
                               u16* __restrict__ srcS, u16* __restrict__ dstS) {
    int e = blockIdx.x * blockDim.x + threadIdx.x;
    if (e < NE) {
        int d = dst[e];
        int p = atomicAdd(cursor + d, 1);
        perm[p] = e;
        srcS[p] = (u16)src[e];
        dstS[p] = (u16)d;
    }
}

// ---------------------------------------------------------------- node-level GEMMs
template<bool IN_BF16>
__global__ void __launch_bounds__(256, 4)
node_pre_kernel(const float* __restrict__ inF, const bf16* __restrict__ inB,
                const bf16* __restrict__ WT,       // [512][128]
                const float* __restrict__ bias0,
                bf16* __restrict__ O1, bf16* __restrict__ O2) {
    const int half = blockIdx.y;
    const int r0 = blockIdx.x * 64;
    const int t = threadIdx.x, wv = t >> 6, l = t & 63, lr = l & 15, qk = l >> 4;
    int row[4];
#pragma unroll
    for (int m = 0; m < 4; ++m) { int r = r0 + m * 16 + lr; row[m] = r < NN ? r : NN - 1; }
    int coln[4];
#pragma unroll
    for (int n = 0; n < 4; ++n) coln[n] = wv * 64 + n * 16 + lr;
    f32x4 acc[4][4];
#pragma unroll
    for (int m = 0; m < 4; ++m)
#pragma unroll
        for (int n = 0; n < 4; ++n) acc[m][n] = 0.f;
#pragma unroll
    for (int ks = 0; ks < 4; ++ks) {
        const int kg = ks * 32 + qk * 8;
        bf16x8 a[4], b[4];
#pragma unroll
        for (int m = 0; m < 4; ++m)
            a[m] = IN_BF16 ? ld8(inB + row[m] * D + kg) : cvt8(inF + row[m] * D + kg);
#pragma unroll
        for (int n = 0; n < 4; ++n) b[n] = ld8(WT + (half * 256 + coln[n]) * 128 + kg);
#pragma unroll
        for (int m = 0; m < 4; ++m)
#pragma unroll
            for (int n = 0; n < 4; ++n) acc[m][n] = mfma16(a[m], b[n], acc[m][n]);
    }
    bf16* O = half ? O2 : O1;
#pragma unroll
    for (int n = 0; n < 4; ++n) {
        float bia = (half == 0 && bias0) ? bias0[coln[n]] : 0.f;
#pragma unroll
        for (int m = 0; m < 4; ++m)
#pragma unroll
            for (int j = 0; j < 4; ++j) {
                int gr = r0 + m * 16 + qk * 4 + j;
                if (gr < NN) O[gr * 256 + coln[n]] = (bf16)(acc[m][n][j] + bia);
            }
    }
}

// S[r][c] += h1[r] @ WtopT[c]
template<bool HBF>
__global__ void __launch_bounds__(256, 4)
s2_update_kernel(const void* __restrict__ h1, const bf16* __restrict__ WtopT,
                 bf16* __restrict__ S) {
    const int r0 = blockIdx.x * 64;
    const int t = threadIdx.x, wv = t >> 6, l = t & 63, lr = l & 15, qk = l >> 4;
    int row[4];
#pragma unroll
    for (int m = 0; m < 4; ++m) { int r = r0 + m * 16 + lr; row[m] = r < NN ? r : NN - 1; }
    int coln[4];
#pragma unroll
    for (int n = 0; n < 4; ++n) coln[n] = wv * 64 + n * 16 + lr;
    f32x4 acc[4][4];
#pragma unroll
    for (int m = 0; m < 4; ++m)
#pragma unroll
        for (int n = 0; n < 4; ++n) acc[m][n] = 0.f;
#pragma unroll
    for (int ks = 0; ks < 4; ++ks) {
        const int kg = ks * 32 + qk * 8;
        bf16x8 a[4], b[4];
#pragma unroll
        for (int m = 0; m < 4; ++m) {
            if constexpr (HBF) a[m] = ld8((const bf16*)h1 + row[m] * D + kg);
            else               a[m] = cvt8((const float*)h1 + row[m] * D + kg);
        }
#pragma unroll
        for (int n = 0; n < 4; ++n) b[n] = ld8(WtopT + coln[n] * 128 + kg);
#pragma unroll
        for (int m = 0; m < 4; ++m)
#pragma unroll
            for (int n = 0; n < 4; ++n) acc[m][n] = mfma16(a[m], b[n], acc[m][n]);
    }
#pragma unroll
    for (int n = 0; n < 4; ++n)
#pragma unroll
        for (int m = 0; m < 4; ++m)
#pragma unroll
            for (int j = 0; j < 4; ++j) {
                int gr = r0 + m * 16 + qk * 4 + j;
                if (gr < NN) {
                    int idx = gr * 256 + coln[n];
                    S[idx] = (bf16)((float)S[idx] + acc[m][n][j]);
                }
            }
}

// ---------------------------------------------------------------- segment sum (one wave per dst)
__global__ void __launch_bounds__(256, 8)
seg_sum_kernel(const bf16* __restrict__ S, const bf16* __restrict__ Bm,
               const int* __restrict__ offsets, const u16* __restrict__ srcS,
               bf16* __restrict__ T) {
    const int gw = (blockIdx.x * blockDim.x + threadIdx.x) >> 6;
    if (gw >= NN) return;
    const int l = threadIdx.x & 63;
    const int beg = offsets[gw], end = offsets[gw + 1];
    bf16x4 bv = *reinterpret_cast<const bf16x4*>(Bm + (size_t)gw * 256 + l * 4);
    const float b0 = (float)bv[0], b1 = (float)bv[1], b2 = (float)bv[2], b3 = (float)bv[3];
    float t0 = 0.f, t1 = 0.f, t2 = 0.f, t3 = 0.f;
    int i = beg;
    for (; i + 2 <= end; i += 2) {
        int s0 = srcS[i];
        int s1 = srcS[i + 1];
        bf16x4 a0 = *reinterpret_cast<const bf16x4*>(S + (size_t)s0 * 256 + l * 4);
        bf16x4 a1 = *reinterpret_cast<const bf16x4*>(S + (size_t)s1 * 256 + l * 4);
        float v;
        v = (float)a0[0] + b0; t0 += v > 0.f ? v : 0.f;
        v = (float)a0[1] + b1; t1 += v > 0.f ? v : 0.f;
        v = (float)a0[2] + b2; t2 += v > 0.f ? v : 0.f;
        v = (float)a0[3] + b3; t3 += v > 0.f ? v : 0.f;
        v = (float)a1[0] + b0; t0 += v > 0.f ? v : 0.f;
        v = (float)a1[1] + b1; t1 += v > 0.f ? v : 0.f;
        v = (float)a1[2] + b2; t2 += v > 0.f ? v : 0.f;
        v = (float)a1[3] + b3; t3 += v > 0.f ? v : 0.f;
    }
    if (i < end) {
        int s0 = srcS[i];
        bf16x4 a0 = *reinterpret_cast<const bf16x4*>(S + (size_t)s0 * 256 + l * 4);
        float v;
        v = (float)a0[0] + b0; t0 += v > 0.f ? v : 0.f;
        v = (float)a0[1] + b1; t1 += v > 0.f ? v : 0.f;
        v = (float)a0[2] + b2; t2 += v > 0.f ? v : 0.f;
        v = (float)a0[3] + b3; t3 += v > 0.f ? v : 0.f;
    }
    bf16x4 o;
    o[0] = (bf16)t0; o[1] = (bf16)t1; o[2] = (bf16)t2; o[3] = (bf16)t3;
    *reinterpret_cast<bf16x4*>(T + (size_t)gw * 256 + l * 4) = o;
}

// h[r] = T[r] @ We2T + deg[r]*b_e2   (bf16 out)
__global__ void __launch_bounds__(256, 4)
h_gemm_kernel(const bf16* __restrict__ T, const bf16* __restrict__ We2T,
              const float* __restrict__ b_e2, const int* __restrict__ deg,
              bf16* __restrict__ h) {
    const int r0 = blockIdx.x * 64;
    const int t = threadIdx.x, wv = t >> 6, l = t & 63, lr = l & 15, qk = l >> 4;
    int row[4];
#pragma unroll
    for (int m = 0; m < 4; ++m) { int r = r0 + m * 16 + lr; row[m] = r < NN ? r : NN - 1; }
    int col2[2];
#pragma unroll
    for (int n = 0; n < 2; ++n) col2[n] = wv * 32 + n * 16 + lr;
    f32x4 acc[4][2];
#pragma unroll
    for (int m = 0; m < 4; ++m)
#pragma unroll
        for (int n = 0; n < 2; ++n) acc[m][n] = 0.f;
#pragma unroll
    for (int ks = 0; ks < 8; ++ks) {
        const int kg = ks * 32 + qk * 8;
        bf16x8 a[4], b[2];
#pragma unroll
        for (int m = 0; m < 4; ++m) a[m] = ld8(T + (size_t)row[m] * 256 + kg);
#pragma unroll
        for (int n = 0; n < 2; ++n) b[n] = ld8(We2T + col2[n] * 256 + kg);
#pragma unroll
        for (int m = 0; m < 4; ++m)
#pragma unroll
            for (int n = 0; n < 2; ++n) acc[m][n] = mfma16(a[m], b[n], acc[m][n]);
    }
#pragma unroll
    for (int n = 0; n < 2; ++n) {
        float bw = b_e2[col2[n]];
#pragma unroll
        for (int m = 0; m < 4; ++m)
#pragma unroll
            for (int j = 0; j < 4; ++j) {
                int gr = r0 + m * 16 + qk * 4 + j;
                if (gr < NN)
                    h[(size_t)gr * D + col2[n]] = (bf16)(acc[m][n][j] + (float)deg[gr] * bw);
            }
    }
}

// ---------------------------------------------------------------- node MLP (nf2 only)
template<bool HBF>
__global__ void __launch_bounds__(256, 2)
node_mlp_kernel(const float* __restrict__ node_feat,
                const void* __restrict__ h2,
                const bf16* __restrict__ Wn1T,
                const bf16* __restrict__ Wn2T,
                const float* __restrict__ b_n1,
                const float* __restrict__ b_n2,
                bf16* __restrict__ nf2_bf) {
    __shared__ __align__(16) char sH[64 * 512];
    const int t = threadIdx.x, wv = t >> 6, l = t & 63, lr = l & 15, qk = l >> 4;
    const int r0 = blockIdx.x * 64;
    int row[4];
#pragma unroll
    for (int m = 0; m < 4; ++m) { int r = r0 + m * 16 + lr; row[m] = r < NN ? r : NN - 1; }
    int coln[4];
#pragma unroll
    for (int n = 0; n < 4; ++n) coln[n] = wv * 64 + n * 16 + lr;
    f32x4 acc[4][4];
#pragma unroll
    for (int m = 0; m < 4; ++m)
#pragma unroll
        for (int n = 0; n < 4; ++n) acc[m][n] = 0.f;
#pragma unroll
    for (int ks = 0; ks < 4; ++ks) {
        const int kg = ks * 32 + qk * 8;
        bf16x8 a[4], b[4];
#pragma unroll
        for (int m = 0; m < 4; ++m) a[m] = cvt8(node_feat + (size_t)row[m] * D + kg);
#pragma unroll
        for (int n = 0; n < 4; ++n) b[n] = ld8(Wn1T + coln[n] * 256 + kg);
#pragma unroll
        for (int m = 0; m < 4; ++m)
#pragma unroll
            for (int n = 0; n < 4; ++n) acc[m][n] = mfma16(a[m], b[n], acc[m][n]);
#pragma unroll
        for (int m = 0; m < 4; ++m) {
            if constexpr (HBF) a[m] = ld8((const bf16*)h2 + (size_t)row[m] * D + kg);
            else               a[m] = cvt8((const float*)h2 + (size_t)row[m] * D + kg);
        }
#pragma unroll
        for (int n = 0; n < 4; ++n) b[n] = ld8(Wn1T + coln[n] * 256 + 128 + kg);
#pragma unroll
        for (int m = 0; m < 4; ++m)
#pragma unroll
            for (int n = 0; n < 4; ++n) acc[m][n] = mfma16(a[m], b[n], acc[m][n]);
    }
#pragma unroll
    for (int n = 0; n < 4; ++n) {
        float bia = b_n1[coln[n]];
#pragma unroll
        for (int m = 0; m < 4; ++m)
#pragma unroll
            for (int j = 0; j < 4; ++j) {
                int r = m * 16 + qk * 4 + j;
                float v = acc[m][n][j] + bia;
                v = v > 0.f ? v : 0.f;
                *reinterpret_cast<bf16*>(sH + swz512(r, coln[n] * 2)) = (bf16)v;
            }
    }
    __syncthreads();
    int col2[2];
#pragma unroll
    for (int n = 0; n < 2; ++n) col2[n] = wv * 32 + n * 16 + lr;
    f32x4 acc2[4][2];
#pragma unroll
    for (int m = 0; m < 4; ++m)
#pragma unroll
        for (int n = 0; n < 2; ++n) acc2[m][n] = 0.f;
#pragma unroll
    for (int ks = 0; ks < 8; ++ks) {
        const int k0 = ks * 32 + qk * 8;
        bf16x8 a[4], b[2];
#pragma unroll
        for (int m = 0; m < 4; ++m)
            a[m] = *reinterpret_cast<const bf16x8*>(sH + swz512(m * 16 + lr, k0 * 2));
#pragma unroll
        for (int n = 0; n < 2; ++n) b[n] = ld8(Wn2T + col2[n] * 256 + k0);
#pragma unroll
        for (int m = 0; m < 4; ++m)
#pragma unroll
            for (int n = 0; n < 2; ++n) acc2[m][n] = mfma16(a[m], b[n], acc2[m][n]);
    }
#pragma unroll
    for (int n = 0; n < 2; ++n) {
        float bia = b_n2[col2[n]];
#pragma unroll
        for (int m = 0; m < 4; ++m)
#pragma unroll
            for (int j = 0; j < 4; ++j) {
                int gr = r0 + m * 16 + qk * 4 + j;
                if (gr < NN) nf2_bf[(size_t)gr * D + col2[n]] = (bf16)(acc2[m][n][j] + bia);
            }
    }
}

// ---------------------------------------------------------------- edge logits (dst-sorted)
// r3 memory behavior (plain cached loads, direct scattered stores); occupancy 8 blocks/CU
__global__ void __launch_bounds__(256, 8)
edge_logit_sorted(const bf16* __restrict__ U, const bf16* __restrict__ V,
                  const int* __restrict__ perm, const u16* __restrict__ srcS,
                  const u16* __restrict__ dstS,
                  const bf16* __restrict__ W2eroT, const bf16* __restrict__ W2lgT,
                  const float* __restrict__ b2ero, const float* __restrict__ b2lg,
                  float* __restrict__ e_ro, float* __restrict__ e_lg) {
    __shared__ int s_e[128];
    __shared__ int s_s[128];
    __shared__ int s_d[128];
    const int t = threadIdx.x, wv = t >> 6, l = t & 63, lr = l & 15, qk = l >> 4;
    const int p0 = blockIdx.x * 128;
    if (t < 128) {
        int p = min(p0 + t, NE - 1);
        s_e[t] = perm[p];
        s_s[t] = (int)srcS[p];
        s_d[t] = (int)dstS[p];
    }
    __syncthreads();

    int is[2], id[2];
#pragma unroll
    for (int m = 0; m < 2; ++m) {
        int el = wv * 32 + m * 16 + lr;
        is[m] = s_s[el];
        id[m] = s_d[el];
    }
    f32x4 aro[2][8];
    f32x4 alg[2];
#pragma unroll
    for (int m = 0; m < 2; ++m) {
        alg[m] = 0.f;
#pragma unroll
        for (int n = 0; n < 8; ++n) aro[m][n] = 0.f;
    }
#pragma unroll
    for (int ks = 0; ks < 8; ++ks) {
        const int kg = ks * 32 + qk * 8;
        bf16x8 a[2];
#pragma unroll
        for (int m = 0; m < 2; ++m) {
            bf16x8 us = ld8(U + (size_t)is[m] * 256 + kg);
            bf16x8 vd = ld8(V + (size_t)id[m] * 256 + kg);
            bf16x8 ud = ld8(U + (size_t)id[m] * 256 + kg);
            bf16x8 vs = ld8(V + (size_t)is[m] * 256 + kg);
#pragma unroll
            for (int i = 0; i < 8; ++i) {
                float f1 = (float)us[i] + (float)vd[i]; f1 = f1 > 0.f ? f1 : 0.f;
                float f2 = (float)ud[i] + (float)vs[i]; f2 = f2 > 0.f ? f2 : 0.f;
                a[m][i] = (bf16)(f1 + f2);
            }
        }
#pragma unroll
        for (int n = 0; n < 8; ++n) {
            bf16x8 b = ld8(W2eroT + (n * 16 + lr) * 256 + kg);
#pragma unroll
            for (int m = 0; m < 2; ++m) aro[m][n] = mfma16(a[m], b, aro[m][n]);
        }
        bf16x8 blg = ld8(W2lgT + lr * 256 + kg);
#pragma unroll
        for (int m = 0; m < 2; ++m) alg[m] = mfma16(a[m], blg, alg[m]);
    }
#pragma unroll
    for (int n = 0; n < 8; ++n) {
        int col = n * 16 + lr;
        float bia = b2ero[col];
#pragma unroll
        for (int m = 0; m < 2; ++m)
#pragma unroll
            for (int j = 0; j < 4; ++j) {
                int el = wv * 32 + m * 16 + qk * 4 + j;
                e_ro[(size_t)s_e[el] * D + col] = aro[m][n][j] + bia;
            }
    }
    if (lr < 2) {
        float bia = b2lg[lr];
#pragma unroll
        for (int m = 0; m < 2; ++m)
#pragma unroll
            for (int j = 0; j < 4; ++j) {
                int el = wv * 32 + m * 16 + qk * 4 + j;
                e_lg[(size_t)s_e[el] * 2 + lr] = alg[m][j] + bia;
            }
    }
}

// ---------------------------------------------------------------- fallback kernels (round-2 path)
__global__ void __launch_bounds__(256, 4)
edge_msg_kernel(const bf16* __restrict__ S, const bf16* __restrict__ Bm,
                const int* __restrict__ src, const int* __restrict__ dst,
                const bf16* __restrict__ We2T,
                const float* __restrict__ b_e2,
                float* __restrict__ h_out) {
    __shared__ int s_src[128];
    __shared__ int s_dst[128];
    const int t = threadIdx.x, wv = t >> 6, l = t & 63, lr = l & 15, qk = l >> 4;
    const int e0 = blockIdx.x * 128;
    if (t < 128)      s_src[t] = src[min(e0 + t, NE - 1)];
    else              s_dst[t - 128] = dst[min(e0 + t - 128, NE - 1)];
    __syncthreads();
    const bf16* pS[2];
    const bf16* pB[2];
#pragma unroll
    for (int m = 0; m < 2; ++m) {
        int el = wv * 32 + m * 16 + lr;
        pS[m] = S + s_src[el] * 256;
        pB[m] = Bm + s_dst[el] * 256;
    }
    f32x4 acc[2][8];
#pragma unroll
    for (int m = 0; m < 2; ++m)
#pragma unroll
        for (int n = 0; n < 8; ++n) acc[m][n] = 0.f;
#pragma unroll
    for (int ks = 0; ks < 8; ++ks) {
        const int kg = ks * 32 + qk * 8;
        bf16x8 a[2];
#pragma unroll
        for (int m = 0; m < 2; ++m) {
            bf16x8 sa = ld8(pS[m] + kg);
            bf16x8 sb = ld8(pB[m] + kg);
#pragma unroll
            for (int i = 0; i < 8; ++i) {
                float f = (float)sa[i] + (float)sb[i];
                a[m][i] = (bf16)(f > 0.f ? f : 0.f);
            }
        }
#pragma unroll
        for (int n = 0; n < 8; ++n) {
            bf16x8 b = ld8(We2T + (n * 16 + lr) * 256 + kg);
#pragma unroll
            for (int m = 0; m < 2; ++m) acc[m][n] = mfma16(a[m], b, acc[m][n]);
        }
    }
#pragma unroll
    for (int n = 0; n < 8; ++n) {
        int col = n * 16 + lr;
        float bia = b_e2[col];
#pragma unroll
        for (int m = 0; m < 2; ++m)
#pragma unroll
            for (int j = 0; j < 4; ++j) {
                int el = wv * 32 + m * 16 + qk * 4 + j;
                if (e0 + el < NE)
                    atomicAdd(h_out + s_dst[el] * D + col, acc[m][n][j] + bia);
            }
    }
}

__global__ void __launch_bounds__(256, 4)
edge_logit_fast(const bf16* __restrict__ U, const bf16* __restrict__ V,
                const int* __restrict__ src, const int* __restrict__ dst,
                const bf16* __restrict__ W2eroT,
                const bf16* __restrict__ W2lgT,
                const float* __restrict__ b2ero, const float* __restrict__ b2lg,
                float* __restrict__ e_ro, float* __restrict__ e_lg) {
    __shared__ int s_src[128];
    __shared__ int s_dst[128];
    const int t = threadIdx.x, wv = t >> 6, l = t & 63, lr = l & 15, qk = l >> 4;
    const int e0 = blockIdx.x * 128;
    if (t < 128)      s_src[t] = src[min(e0 + t, NE - 1)];
    else              s_dst[t - 128] = dst[min(e0 + t - 128, NE - 1)];
    __syncthreads();
    int is[2], id[2];
#pragma unroll
    for (int m = 0; m < 2; ++m) {
        int el = wv * 32 + m * 16 + lr;
        is[m] = s_src[el];
        id[m] = s_dst[el];
    }
    f32x4 aro[2][8];
    f32x4 alg[2];
#pragma unroll
    for (int m = 0; m < 2; ++m) {
        alg[m] = 0.f;
#pragma unroll
        for (int n = 0; n < 8; ++n) aro[m][n] = 0.f;
    }
#pragma unroll
    for (int ks = 0; ks < 8; ++ks) {
        const int kg = ks * 32 + qk * 8;
        bf16x8 a[2];
#pragma unroll
        for (int m = 0; m < 2; ++m) {
            bf16x8 us = ld8(U + is[m] * 256 + kg);
            bf16x8 vd = ld8(V + id[m] * 256 + kg);
            bf16x8 ud = ld8(U + id[m] * 256 + kg);
            bf16x8 vs = ld8(V + is[m] * 256 + kg);
#pragma unroll
            for (int i = 0; i < 8; ++i) {
                float f1 = (float)us[i] + (float)vd[i]; f1 = f1 > 0.f ? f1 : 0.f;
                float f2 = (float)ud[i] + (float)vs[i]; f2 = f2 > 0.f ? f2 : 0.f;
                a[m][i] = (bf16)(f1 + f2);
            }
        }
#pragma unroll
        for (int n = 0; n < 8; ++n) {
            bf16x8 b = ld8(W2eroT + (n * 16 + lr) * 256 + kg);
#pragma unroll
            for (int m = 0; m < 2; ++m) aro[m][n] = mfma16(a[m], b, aro[m][n]);
        }
        bf16x8 blg = ld8(W2lgT + lr * 256 + kg);
#pragma unroll
        for (int m = 0; m < 2; ++m) alg[m] = mfma16(a[m], blg, alg[m]);
    }
#pragma unroll
    for (int n = 0; n < 8; ++n) {
        int col = n * 16 + lr;
        float bia = b2ero[col];
#pragma unroll
        for (int m = 0; m < 2; ++m)
#pragma unroll
            for (int j = 0; j < 4; ++j) {
                int el = wv * 32 + m * 16 + qk * 4 + j;
                int e = e0 + el;
                if (e < NE) e_ro[e * D + col] = aro[m][n][j] + bia;
            }
    }
    if (lr < 2) {
        float bia = b2lg[lr];
#pragma unroll
        for (int m = 0; m < 2; ++m)
#pragma unroll
            for (int j = 0; j < 4; ++j) {
                int el = wv * 32 + m * 16 + qk * 4 + j;
                int e = e0 + el;
                if (e < NE) e_lg[e * 2 + lr] = alg[m][j] + bia;
            }
    }
}

// ---------------------------------------------------------------- n_out readout
__global__ void __launch_bounds__(256, 4)
nro_kernel(const bf16* __restrict__ nf2_bf, const bf16* __restrict__ WnroT,
           const float* __restrict__ b_nro, float* __restrict__ n_out) {
    const int r0 = blockIdx.x * 64;
    const int t = threadIdx.x, wv = t >> 6, l = t & 63, lr = l & 15, qk = l >> 4;
    int row[4];
#pragma unroll
    for (int m = 0; m < 4; ++m) { int r = r0 + m * 16 + lr; row[m] = r < NN ? r : NN - 1; }
    int col2[2];
#pragma unroll
    for (int n = 0; n < 2; ++n) col2[n] = wv * 32 + n * 16 + lr;
    f32x4 acc[4][2];
#pragma unroll
    for (int m = 0; m < 4; ++m)
#pragma unroll
        for (int n = 0; n < 2; ++n) acc[m][n] = 0.f;
#pragma unroll
    for (int ks = 0; ks < 4; ++ks) {
        const int kg = ks * 32 + qk * 8;
        bf16x8 a[4], b[2];
#pragma unroll
        for (int m = 0; m < 4; ++m) a[m] = ld8(nf2_bf + (size_t)row[m] * D + kg);
#pragma unroll
        for (int n = 0; n < 2; ++n) b[n] = ld8(WnroT + col2[n] * 128 + kg);
#pragma unroll
        for (int m = 0; m < 4; ++m)
#pragma unroll
            for (int n = 0; n < 2; ++n) acc[m][n] = mfma16(a[m], b[n], acc[m][n]);
    }
#pragma unroll
    for (int n = 0; n < 2; ++n) {
        float bia = b_nro[col2[n]];
#pragma unroll
        for (int m = 0; m < 4; ++m)
#pragma unroll
            for (int j = 0; j < 4; ++j) {
                int gr = r0 + m * 16 + qk * 4 + j;
                if (gr < NN) n_out[(size_t)gr * D + col2[n]] = acc[m][n][j] + bia;
            }
    }
}

// ---------------------------------------------------------------- launch
extern "C" void kernel_launch(void* const* d_in, const int* in_sizes, int n_in,
                              void* d_out, int out_size, void* d_ws, size_t ws_size,
                              hipStream_t stream) {
    const float* node_feat = (const float*)d_in[0];
    const int*   src   = (const int*)d_in[1];
    const int*   dst   = (const int*)d_in[2];
    const float* W_e1  = (const float*)d_in[3];
    const float* b_e1  = (const float*)d_in[4];
    const float* W_e2  = (const float*)d_in[5];
    const float* b_e2  = (const float*)d_in[6];
    const float* W_n1  = (const float*)d_in[7];
    const float* b_n1  = (const float*)d_in[8];
    const float* W_n2  = (const float*)d_in[9];
    const float* b_n2  = (const float*)d_in[10];
    const float* W_el1 = (const float*)d_in[11];
    const float* b_el1 = (const float*)d_in[12];
    const float* W_el2 = (const float*)d_in[13];
    const float* b_el2 = (const float*)d_in[14];
    const float* W_logit = (const float*)d_in[15];
    const float* b_logit = (const float*)d_in[16];
    const float* W_nro = (const float*)d_in[17];
    const float* b_nro = (const float*)d_in[18];
    const float* W_ero = (const float*)d_in[19];
    const float* b_ero = (const float*)d_in[20];

    char* ws = (char*)d_ws;
    bf16* wb = (bf16*)ws;
    bf16* WmbT   = wb;            // [512][128]
    bf16* WtopT  = wb + 65536;    // [256][128]
    bf16* We2T   = wb + 98304;    // [128][256]
    bf16* Wn1T   = wb + 131072;   // [256][256]
    bf16* Wn2T   = wb + 196608;   // [128][256]
    bf16* WuvT   = wb + 229376;   // [512][128]
    bf16* WnroT  = wb + 294912;   // [128][128]
    bf16* W2eroT = wb + 311296;   // [128][256]
    bf16* W2lgT  = wb + 344064;   // [16][256]
    float* fb    = (float*)(ws + 928000);
    float* b2ero = fb;
    float* b2lg  = fb + 128;

    float* out   = (float*)d_out;
    float* n_out = out;                 // NN*128 f32 (15.36 MB)
    float* e_ro  = out + 3840000;       // NE*128 f32 (307.2 MB)
    float* e_lg  = out + 80640000;      // NE*2 f32 (4.8 MB)

    TPack pk;
    pk.m[0]  = {W_e1 + 128 * 256, WmbT,              128, 256};
    pk.m[1]  = {W_e1 + 256 * 256, WmbT + 256 * 128,  128, 256};
    pk.m[2]  = {W_e1,             WtopT,             128, 256};
    pk.m[3]  = {W_e2,             We2T,              256, 128};
    pk.m[4]  = {W_n1,             Wn1T,              256, 256};
    pk.m[5]  = {W_n2,             Wn2T,              256, 128};
    pk.m[6]  = {W_el1,            WuvT,              128, 256};
    pk.m[7]  = {W_el1 + 128 * 256, WuvT + 256 * 128, 128, 256};
    pk.m[8]  = {W_nro,            WnroT,             128, 128};
    pk.m[9]  = {W_nro,            WnroT,             128, 128};
    pk.m[10] = {W_nro,            WnroT,             128, 128};
    pk.m[11] = {W_nro,            WnroT,             128, 128};

    const size_t NEED_NEW = 28888576;

    if (ws_size >= NEED_NEW) {
        // ---------------- dst-sorted CSR, atomic-free ----------------
        char* eb = (char*)e_ro;   // 307.2 MB of dead-until-logit space
        bf16* S    = (bf16*)(eb);
        bf16* Bm   = (bf16*)(eb + 15360000);
        bf16* T    = (bf16*)(eb + 30720000);
        bf16* h1   = (bf16*)(eb + 46080000);
        bf16* h2   = (bf16*)(eb + 53760000);
        int* counts  = (int*)(eb + 61440000);
        int* offsets = (int*)(eb + 61560000);
        int* cursor  = (int*)(eb + 61680004);
        bf16* U    = (bf16*)n_out;           // dead until nro (runs last)
        bf16* nf2_bf = (bf16*)(ws + 1048576);
        bf16* Vbuf   = (bf16*)(ws + 8728576);
        int*  perm   = (int*)(ws + 24088576);
        u16*  srcS   = (u16*)(ws + 26488576);
        u16*  dstS   = (u16*)(ws + 27688576);

        transpose_cast_kernel<<<dim3(12, 40), 256, 0, stream>>>(pk);
        fuse_kernel<<<257, 160, 0, stream>>>(W_el2, W_ero, W_logit, b_el2, b_ero, b_logit,
                                             W2eroT, W2lgT, b2ero, b2lg);
        hipMemsetAsync(counts, 0, NN * 4, stream);
        hist_kernel<<<(NE + 255) / 256, 256, 0, stream>>>(dst, counts);
        scan_kernel<<<1, 1024, 0, stream>>>(counts, offsets, cursor);
        scatter_kernel<<<(NE + 255) / 256, 256, 0, stream>>>(src, dst, cursor,
                                                             perm, srcS, dstS);
        node_pre_kernel<false><<<dim3(469, 2), 256, 0, stream>>>(
            node_feat, nullptr, WmbT, b_e1, S, Bm);
        seg_sum_kernel<<<7500, 256, 0, stream>>>(S, Bm, offsets, srcS, T);
        h_gemm_kernel<<<469, 256, 0, stream>>>(T, We2T, b_e2, counts, h1);
        s2_update_kernel<true><<<469, 256, 0, stream>>>(h1, WtopT, S);
        seg_sum_kernel<<<7500, 256, 0, stream>>>(S, Bm, offsets, srcS, T);
        h_gemm_kernel<<<469, 256, 0, stream>>>(T, We2T, b_e2, counts, h2);
        node_mlp_kernel<true><<<469, 256, 0, stream>>>(
            node_feat, h2, Wn1T, Wn2T, b_n1, b_n2, nf2_bf);
        node_pre_kernel<true><<<dim3(469, 2), 256, 0, stream>>>(
            nullptr, nf2_bf, WuvT, b_el1, U, Vbuf);
        edge_logit_sorted<<<4688, 256, 0, stream>>>(
            U, Vbuf, perm, srcS, dstS, W2eroT, W2lgT, b2ero, b2lg, e_ro, e_lg);
        nro_kernel<<<469, 256, 0, stream>>>(nf2_bf, WnroT, b_nro, n_out);
    } else {
        // ---------------- fallback: round-2 proven path ----------------
        bf16* nf2_bf = (bf16*)(ws + 1048576);
        bf16* Vbuf   = (bf16*)(ws + 9000000);
        float* h1f = n_out;
        bf16*  S   = (bf16*)e_ro;
        bf16*  Bm  = (bf16*)((char*)e_ro + 15360000);
        float* h2f = (float*)((char*)e_ro + 30720000);
        bf16*  U   = (bf16*)n_out;

        transpose_cast_kernel<<<dim3(12, 40), 256, 0, stream>>>(pk);
        fuse_kernel<<<257, 160, 0, stream>>>(W_el2, W_ero, W_logit, b_el2, b_ero, b_logit,
                                             W2eroT, W2lgT, b2ero, b2lg);
        hipMemsetAsync(h1f, 0, (size_t)NN * D * 4, stream);
        hipMemsetAsync(h2f, 0, (size_t)NN * D * 4, stream);
        node_pre_kernel<false><<<dim3(469, 2), 256, 0, stream>>>(
            node_feat, nullptr, WmbT, b_e1, S, Bm);
        edge_msg_kernel<<<4688, 256, 0, stream>>>(S, Bm, src, dst, We2T, b_e2, h1f);
        s2_update_kernel<false><<<469, 256, 0, stream>>>(h1f, WtopT, S);
        edge_msg_kernel<<<4688, 256, 0, stream>>>(S, Bm, src, dst, We2T, b_e2, h2f);
        node_mlp_kernel<false><<<469, 256, 0, stream>>>(
            node_feat, h2f, Wn1T, Wn2T, b_n1, b_n2, nf2_bf);
        node_pre_kernel<true><<<dim3(469, 2), 256, 0, stream>>>(
            nullptr, nf2_bf, WuvT, b_el1, U, Vbuf);
        edge_logit_fast<<<4688, 256, 0, stream>>>(
            U, Vbuf, src, dst, W2eroT, W2lgT, b2ero, b2lg, e_ro, e_lg);
        nro_kernel<<<469, 256, 0, stream>>>(nf2_bf, WnroT, b_nro, n_out);
    }
}

// Round 7
// 754.230 us; speedup vs baseline: 2.3028x; 2.2191x over previous
//
#include <hip/hip_runtime.h>
#include <hip/hip_bf16.h>

typedef __bf16 bf16;
typedef unsigned short u16;
typedef bf16 bf16x8 __attribute__((ext_vector_type(8)));
typedef bf16 bf16x4 __attribute__((ext_vector_type(4)));
typedef float f32x4 __attribute__((ext_vector_type(4)));

constexpr int NN = 30000;
constexpr int NE = 600000;
constexpr int D  = 128;

__device__ inline f32x4 mfma16(bf16x8 a, bf16x8 b, f32x4 c) {
    return __builtin_amdgcn_mfma_f32_16x16x32_bf16(a, b, c, 0, 0, 0);
}
__device__ inline bf16x8 ld8(const bf16* p) {
    return *reinterpret_cast<const bf16x8*>(p);
}
__device__ inline bf16x8 cvt8(const float* p) {
    float4 v0 = reinterpret_cast<const float4*>(p)[0];
    float4 v1 = reinterpret_cast<const float4*>(p)[1];
    bf16x8 r;
    r[0] = (bf16)v0.x; r[1] = (bf16)v0.y; r[2] = (bf16)v0.z; r[3] = (bf16)v0.w;
    r[4] = (bf16)v1.x; r[5] = (bf16)v1.y; r[6] = (bf16)v1.z; r[7] = (bf16)v1.w;
    return r;
}
__device__ inline int swz512(int row, int byteInRow) {
    return row * 512 + (byteInRow ^ ((row & 15) << 4));
}

// ---------------------------------------------------------------- prep
struct TMat { const float* src; bf16* dst; int K; int Nc; };
struct TPack { TMat m[12]; };

__global__ void transpose_cast_kernel(TPack p) {
    TMat mm = p.m[blockIdx.x];
    int total = mm.K * mm.Nc;
    for (int idx = blockIdx.y * blockDim.x + threadIdx.x; idx < total;
         idx += gridDim.y * blockDim.x) {
        int c = idx / mm.K;
        int k = idx - c * mm.K;
        mm.dst[idx] = (bf16)mm.src[k * mm.Nc + c];
    }
}

__global__ void fuse_kernel(const float* __restrict__ W_el2,
                            const float* __restrict__ W_ero,
                            const float* __restrict__ W_logit,
                            const float* __restrict__ b_el2,
                            const float* __restrict__ b_ero,
                            const float* __restrict__ b_logit,
                            bf16* __restrict__ W2eroT, bf16* __restrict__ W2lgT,
                            float* __restrict__ b2ero, float* __restrict__ b2lg) {
    int k = blockIdx.x;
    int c = threadIdx.x;
    if (c >= 144) return;
    if (k < 256) {
        if (c < 128) {
            float s = 0.f;
            for (int j = 0; j < 128; ++j) s += W_el2[k * 128 + j] * W_ero[j * 128 + c];
            W2eroT[c * 256 + k] = (bf16)s;
        } else {
            int cc = c - 128;
            float s = 0.f;
            if (cc < 2) for (int j = 0; j < 128; ++j) s += W_el2[k * 128 + j] * W_logit[j * 2 + cc];
            W2lgT[cc * 256 + k] = (bf16)s;
        }
    } else {
        if (c < 128) {
            float s = b_ero[c];
            for (int j = 0; j < 128; ++j) s += 2.f * b_el2[j] * W_ero[j * 128 + c];
            b2ero[c] = s;
        } else if (c < 130) {
            int cc = c - 128;
            float s = b_logit[cc];
            for (int j = 0; j < 128; ++j) s += 2.f * b_el2[j] * W_logit[j * 2 + cc];
            b2lg[cc] = s;
        }
    }
}

// ---------------------------------------------------------------- sort (counting sort by dst)
__global__ void hist_kernel(const int* __restrict__ dst, int* __restrict__ counts) {
    int e = blockIdx.x * blockDim.x + threadIdx.x;
    if (e < NE) atomicAdd(counts + dst[e], 1);
}

// single-pass block scan: 1024 threads x 30 entries each
__global__ void scan_kernel(const int* __restrict__ counts, int* __restrict__ offsets,
                            int* __restrict__ cursor) {
    __shared__ int part[1024];
    const int t = threadIdx.x;
    const int base = t * 30;
    int local[30];
    int s = 0;
#pragma unroll
    for (int i = 0; i < 30; ++i) {
        int idx = base + i;
        int v = (idx < NN) ? counts[idx] : 0;
        local[i] = s;
        s += v;
    }
    part[t] = s;
    __syncthreads();
    for (int off = 1; off < 1024; off <<= 1) {
        int x = (t >= off) ? part[t - off] : 0;
        __syncthreads();
        part[t] += x;
        __syncthreads();
    }
    int chunkExcl = (t == 0) ? 0 : part[t - 1];
#pragma unroll
    for (int i = 0; i < 30; ++i) {
        int idx = base + i;
        if (idx < NN) {
            int excl = chunkExcl + local[i];
            offsets[idx] = excl;
            cursor[idx] = excl;
        }
    }
    if (t == 0) offsets[NN] = NE;
}

__global__ void scatter_kernel(const int* __restrict__ src, const int* __restrict__ dst,
                               int* __restrict__ cursor, int* __restrict__ perm,
                               u16* __restrict__ srcS, u16* __restrict__ dstS) {
    int e = blockIdx.x * blockDim.x + threadIdx.x;
    if (e < NE) {
        int d = dst[e];
        int p = atomicAdd(cursor + d, 1);
        perm[p] = e;
        srcS[p] = (u16)src[e];
        dstS[p] = (u16)d;
    }
}

// ---------------------------------------------------------------- node-level GEMMs
template<bool IN_BF16>
__global__ void __launch_bounds__(256, 4)
node_pre_kernel(const float* __restrict__ inF, const bf16* __restrict__ inB,
                const bf16* __restrict__ WT,       // [512][128]
                const float* __restrict__ bias0,
                bf16* __restrict__ O1, bf16* __restrict__ O2) {
    const int half = blockIdx.y;
    const int r0 = blockIdx.x * 64;
    const int t = threadIdx.x, wv = t >> 6, l = t & 63, lr = l & 15, qk = l >> 4;
    int row[4];
#pragma unroll
    for (int m = 0; m < 4; ++m) { int r = r0 + m * 16 + lr; row[m] = r < NN ? r : NN - 1; }
    int coln[4];
#pragma unroll
    for (int n = 0; n < 4; ++n) coln[n] = wv * 64 + n * 16 + lr;
    f32x4 acc[4][4];
#pragma unroll
    for (int m = 0; m < 4; ++m)
#pragma unroll
        for (int n = 0; n < 4; ++n) acc[m][n] = 0.f;
#pragma unroll
    for (int ks = 0; ks < 4; ++ks) {
        const int kg = ks * 32 + qk * 8;
        bf16x8 a[4], b[4];
#pragma unroll
        for (int m = 0; m < 4; ++m)
            a[m] = IN_BF16 ? ld8(inB + row[m] * D + kg) : cvt8(inF + row[m] * D + kg);
#pragma unroll
        for (int n = 0; n < 4; ++n) b[n] = ld8(WT + (half * 256 + coln[n]) * 128 + kg);
#pragma unroll
        for (int m = 0; m < 4; ++m)
#pragma unroll
            for (int n = 0; n < 4; ++n) acc[m][n] = mfma16(a[m], b[n], acc[m][n]);
    }
    bf16* O = half ? O2 : O1;
#pragma unroll
    for (int n = 0; n < 4; ++n) {
        float bia = (half == 0 && bias0) ? bias0[coln[n]] : 0.f;
#pragma unroll
        for (int m = 0; m < 4; ++m)
#pragma unroll
            for (int j = 0; j < 4; ++j) {
                int gr = r0 + m * 16 + qk * 4 + j;
                if (gr < NN) O[gr * 256 + coln[n]] = (bf16)(acc[m][n][j] + bia);
            }
    }
}

// S[r][c] += h1[r] @ WtopT[c]
template<bool HBF>
__global__ void __launch_bounds__(256, 4)
s2_update_kernel(const void* __restrict__ h1, const bf16* __restrict__ WtopT,
                 bf16* __restrict__ S) {
    const int r0 = blockIdx.x * 64;
    const int t = threadIdx.x, wv = t >> 6, l = t & 63, lr = l & 15, qk = l >> 4;
    int row[4];
#pragma unroll
    for (int m = 0; m < 4; ++m) { int r = r0 + m * 16 + lr; row[m] = r < NN ? r : NN - 1; }
    int coln[4];
#pragma unroll
    for (int n = 0; n < 4; ++n) coln[n] = wv * 64 + n * 16 + lr;
    f32x4 acc[4][4];
#pragma unroll
    for (int m = 0; m < 4; ++m)
#pragma unroll
        for (int n = 0; n < 4; ++n) acc[m][n] = 0.f;
#pragma unroll
    for (int ks = 0; ks < 4; ++ks) {
        const int kg = ks * 32 + qk * 8;
        bf16x8 a[4], b[4];
#pragma unroll
        for (int m = 0; m < 4; ++m) {
            if constexpr (HBF) a[m] = ld8((const bf16*)h1 + row[m] * D + kg);
            else               a[m] = cvt8((const float*)h1 + row[m] * D + kg);
        }
#pragma unroll
        for (int n = 0; n < 4; ++n) b[n] = ld8(WtopT + coln[n] * 128 + kg);
#pragma unroll
        for (int m = 0; m < 4; ++m)
#pragma unroll
            for (int n = 0; n < 4; ++n) acc[m][n] = mfma16(a[m], b[n], acc[m][n]);
    }
#pragma unroll
    for (int n = 0; n < 4; ++n)
#pragma unroll
        for (int m = 0; m < 4; ++m)
#pragma unroll
            for (int j = 0; j < 4; ++j) {
                int gr = r0 + m * 16 + qk * 4 + j;
                if (gr < NN) {
                    int idx = gr * 256 + coln[n];
                    S[idx] = (bf16)((float)S[idx] + acc[m][n][j]);
                }
            }
}

// ---------------------------------------------------------------- segment sum (one wave per dst)
__global__ void __launch_bounds__(256, 8)
seg_sum_kernel(const bf16* __restrict__ S, const bf16* __restrict__ Bm,
               const int* __restrict__ offsets, const u16* __restrict__ srcS,
               bf16* __restrict__ T) {
    const int gw = (blockIdx.x * blockDim.x + threadIdx.x) >> 6;
    if (gw >= NN) return;
    const int l = threadIdx.x & 63;
    const int beg = offsets[gw], end = offsets[gw + 1];
    bf16x4 bv = *reinterpret_cast<const bf16x4*>(Bm + (size_t)gw * 256 + l * 4);
    const float b0 = (float)bv[0], b1 = (float)bv[1], b2 = (float)bv[2], b3 = (float)bv[3];
    float t0 = 0.f, t1 = 0.f, t2 = 0.f, t3 = 0.f;
    int i = beg;
    for (; i + 4 <= end; i += 4) {
        int s0 = srcS[i], s1 = srcS[i + 1], s2 = srcS[i + 2], s3 = srcS[i + 3];
        bf16x4 a0 = *reinterpret_cast<const bf16x4*>(S + (size_t)s0 * 256 + l * 4);
        bf16x4 a1 = *reinterpret_cast<const bf16x4*>(S + (size_t)s1 * 256 + l * 4);
        bf16x4 a2 = *reinterpret_cast<const bf16x4*>(S + (size_t)s2 * 256 + l * 4);
        bf16x4 a3 = *reinterpret_cast<const bf16x4*>(S + (size_t)s3 * 256 + l * 4);
        float v;
        v = (float)a0[0] + b0; t0 += v > 0.f ? v : 0.f;
        v = (float)a0[1] + b1; t1 += v > 0.f ? v : 0.f;
        v = (float)a0[2] + b2; t2 += v > 0.f ? v : 0.f;
        v = (float)a0[3] + b3; t3 += v > 0.f ? v : 0.f;
        v = (float)a1[0] + b0; t0 += v > 0.f ? v : 0.f;
        v = (float)a1[1] + b1; t1 += v > 0.f ? v : 0.f;
        v = (float)a1[2] + b2; t2 += v > 0.f ? v : 0.f;
        v = (float)a1[3] + b3; t3 += v > 0.f ? v : 0.f;
        v = (float)a2[0] + b0; t0 += v > 0.f ? v : 0.f;
        v = (float)a2[1] + b1; t1 += v > 0.f ? v : 0.f;
        v = (float)a2[2] + b2; t2 += v > 0.f ? v : 0.f;
        v = (float)a2[3] + b3; t3 += v > 0.f ? v : 0.f;
        v = (float)a3[0] + b0; t0 += v > 0.f ? v : 0.f;
        v = (float)a3[1] + b1; t1 += v > 0.f ? v : 0.f;
        v = (float)a3[2] + b2; t2 += v > 0.f ? v : 0.f;
        v = (float)a3[3] + b3; t3 += v > 0.f ? v : 0.f;
    }
    for (; i < end; ++i) {
        int s0 = srcS[i];
        bf16x4 a0 = *reinterpret_cast<const bf16x4*>(S + (size_t)s0 * 256 + l * 4);
        float v;
        v = (float)a0[0] + b0; t0 += v > 0.f ? v : 0.f;
        v = (float)a0[1] + b1; t1 += v > 0.f ? v : 0.f;
        v = (float)a0[2] + b2; t2 += v > 0.f ? v : 0.f;
        v = (float)a0[3] + b3; t3 += v > 0.f ? v : 0.f;
    }
    bf16x4 o;
    o[0] = (bf16)t0; o[1] = (bf16)t1; o[2] = (bf16)t2; o[3] = (bf16)t3;
    *reinterpret_cast<bf16x4*>(T + (size_t)gw * 256 + l * 4) = o;
}

// h[r] = T[r] @ We2T + deg[r]*b_e2   (bf16 out)
__global__ void __launch_bounds__(256, 4)
h_gemm_kernel(const bf16* __restrict__ T, const bf16* __restrict__ We2T,
              const float* __restrict__ b_e2, const int* __restrict__ deg,
              bf16* __restrict__ h) {
    const int r0 = blockIdx.x * 64;
    const int t = threadIdx.x, wv = t >> 6, l = t & 63, lr = l & 15, qk = l >> 4;
    int row[4];
#pragma unroll
    for (int m = 0; m < 4; ++m) { int r = r0 + m * 16 + lr; row[m] = r < NN ? r : NN - 1; }
    int col2[2];
#pragma unroll
    for (int n = 0; n < 2; ++n) col2[n] = wv * 32 + n * 16 + lr;
    f32x4 acc[4][2];
#pragma unroll
    for (int m = 0; m < 4; ++m)
#pragma unroll
        for (int n = 0; n < 2; ++n) acc[m][n] = 0.f;
#pragma unroll
    for (int ks = 0; ks < 8; ++ks) {
        const int kg = ks * 32 + qk * 8;
        bf16x8 a[4], b[2];
#pragma unroll
        for (int m = 0; m < 4; ++m) a[m] = ld8(T + (size_t)row[m] * 256 + kg);
#pragma unroll
        for (int n = 0; n < 2; ++n) b[n] = ld8(We2T + col2[n] * 256 + kg);
#pragma unroll
        for (int m = 0; m < 4; ++m)
#pragma unroll
            for (int n = 0; n < 2; ++n) acc[m][n] = mfma16(a[m], b[n], acc[m][n]);
    }
#pragma unroll
    for (int n = 0; n < 2; ++n) {
        float bw = b_e2[col2[n]];
#pragma unroll
        for (int m = 0; m < 4; ++m)
#pragma unroll
            for (int j = 0; j < 4; ++j) {
                int gr = r0 + m * 16 + qk * 4 + j;
                if (gr < NN)
                    h[(size_t)gr * D + col2[n]] = (bf16)(acc[m][n][j] + (float)deg[gr] * bw);
            }
    }
}

// ---------------------------------------------------------------- node MLP (nf2 only)
template<bool HBF>
__global__ void __launch_bounds__(256, 2)
node_mlp_kernel(const float* __restrict__ node_feat,
                const void* __restrict__ h2,
                const bf16* __restrict__ Wn1T,
                const bf16* __restrict__ Wn2T,
                const float* __restrict__ b_n1,
                const float* __restrict__ b_n2,
                bf16* __restrict__ nf2_bf) {
    __shared__ __align__(16) char sH[64 * 512];
    const int t = threadIdx.x, wv = t >> 6, l = t & 63, lr = l & 15, qk = l >> 4;
    const int r0 = blockIdx.x * 64;
    int row[4];
#pragma unroll
    for (int m = 0; m < 4; ++m) { int r = r0 + m * 16 + lr; row[m] = r < NN ? r : NN - 1; }
    int coln[4];
#pragma unroll
    for (int n = 0; n < 4; ++n) coln[n] = wv * 64 + n * 16 + lr;
    f32x4 acc[4][4];
#pragma unroll
    for (int m = 0; m < 4; ++m)
#pragma unroll
        for (int n = 0; n < 4; ++n) acc[m][n] = 0.f;
#pragma unroll
    for (int ks = 0; ks < 4; ++ks) {
        const int kg = ks * 32 + qk * 8;
        bf16x8 a[4], b[4];
#pragma unroll
        for (int m = 0; m < 4; ++m) a[m] = cvt8(node_feat + (size_t)row[m] * D + kg);
#pragma unroll
        for (int n = 0; n < 4; ++n) b[n] = ld8(Wn1T + coln[n] * 256 + kg);
#pragma unroll
        for (int m = 0; m < 4; ++m)
#pragma unroll
            for (int n = 0; n < 4; ++n) acc[m][n] = mfma16(a[m], b[n], acc[m][n]);
#pragma unroll
        for (int m = 0; m < 4; ++m) {
            if constexpr (HBF) a[m] = ld8((const bf16*)h2 + (size_t)row[m] * D + kg);
            else               a[m] = cvt8((const float*)h2 + (size_t)row[m] * D + kg);
        }
#pragma unroll
        for (int n = 0; n < 4; ++n) b[n] = ld8(Wn1T + coln[n] * 256 + 128 + kg);
#pragma unroll
        for (int m = 0; m < 4; ++m)
#pragma unroll
            for (int n = 0; n < 4; ++n) acc[m][n] = mfma16(a[m], b[n], acc[m][n]);
    }
#pragma unroll
    for (int n = 0; n < 4; ++n) {
        float bia = b_n1[coln[n]];
#pragma unroll
        for (int m = 0; m < 4; ++m)
#pragma unroll
            for (int j = 0; j < 4; ++j) {
                int r = m * 16 + qk * 4 + j;
                float v = acc[m][n][j] + bia;
                v = v > 0.f ? v : 0.f;
                *reinterpret_cast<bf16*>(sH + swz512(r, coln[n] * 2)) = (bf16)v;
            }
    }
    __syncthreads();
    int col2[2];
#pragma unroll
    for (int n = 0; n < 2; ++n) col2[n] = wv * 32 + n * 16 + lr;
    f32x4 acc2[4][2];
#pragma unroll
    for (int m = 0; m < 4; ++m)
#pragma unroll
        for (int n = 0; n < 2; ++n) acc2[m][n] = 0.f;
#pragma unroll
    for (int ks = 0; ks < 8; ++ks) {
        const int k0 = ks * 32 + qk * 8;
        bf16x8 a[4], b[2];
#pragma unroll
        for (int m = 0; m < 4; ++m)
            a[m] = *reinterpret_cast<const bf16x8*>(sH + swz512(m * 16 + lr, k0 * 2));
#pragma unroll
        for (int n = 0; n < 2; ++n) b[n] = ld8(Wn2T + col2[n] * 256 + k0);
#pragma unroll
        for (int m = 0; m < 4; ++m)
#pragma unroll
            for (int n = 0; n < 2; ++n) acc2[m][n] = mfma16(a[m], b[n], acc2[m][n]);
    }
#pragma unroll
    for (int n = 0; n < 2; ++n) {
        float bia = b_n2[col2[n]];
#pragma unroll
        for (int m = 0; m < 4; ++m)
#pragma unroll
            for (int j = 0; j < 4; ++j) {
                int gr = r0 + m * 16 + qk * 4 + j;
                if (gr < NN) nf2_bf[(size_t)gr * D + col2[n]] = (bf16)(acc2[m][n][j] + bia);
            }
    }
}

// ---------------------------------------------------------------- edge logits (dst-sorted)
// exact r3 config: (256,4), plain cached loads, direct scattered stores;
// + bijective XCD swizzle (grid 4688 = 8*586) for d-side L2 locality.
__global__ void __launch_bounds__(256, 4)
edge_logit_sorted(const bf16* __restrict__ U, const bf16* __restrict__ V,
                  const int* __restrict__ perm, const u16* __restrict__ srcS,
                  const u16* __restrict__ dstS,
                  const bf16* __restrict__ W2eroT, const bf16* __restrict__ W2lgT,
                  const float* __restrict__ b2ero, const float* __restrict__ b2lg,
                  float* __restrict__ e_ro, float* __restrict__ e_lg) {
    __shared__ int s_e[128];
    __shared__ int s_s[128];
    __shared__ int s_d[128];
    const int t = threadIdx.x, wv = t >> 6, l = t & 63, lr = l & 15, qk = l >> 4;
    const int bid = (int)blockIdx.x;
    const int cpx = (int)(gridDim.x >> 3);          // 586, grid divisible by 8
    const int sbid = (bid & 7) * cpx + (bid >> 3);  // XCD-chunked remap
    const int p0 = sbid * 128;
    if (t < 128) {
        int p = min(p0 + t, NE - 1);
        s_e[t] = perm[p];
        s_s[t] = (int)srcS[p];
        s_d[t] = (int)dstS[p];
    }
    __syncthreads();

    int is[2], id[2];
#pragma unroll
    for (int m = 0; m < 2; ++m) {
        int el = wv * 32 + m * 16 + lr;
        is[m] = s_s[el];
        id[m] = s_d[el];
    }
    f32x4 aro[2][8];
    f32x4 alg[2];
#pragma unroll
    for (int m = 0; m < 2; ++m) {
        alg[m] = 0.f;
#pragma unroll
        for (int n = 0; n < 8; ++n) aro[m][n] = 0.f;
    }
#pragma unroll
    for (int ks = 0; ks < 8; ++ks) {
        const int kg = ks * 32 + qk * 8;
        bf16x8 a[2];
#pragma unroll
        for (int m = 0; m < 2; ++m) {
            bf16x8 us = ld8(U + (size_t)is[m] * 256 + kg);
            bf16x8 vd = ld8(V + (size_t)id[m] * 256 + kg);
            bf16x8 ud = ld8(U + (size_t)id[m] * 256 + kg);
            bf16x8 vs = ld8(V + (size_t)is[m] * 256 + kg);
#pragma unroll
            for (int i = 0; i < 8; ++i) {
                float f1 = (float)us[i] + (float)vd[i]; f1 = f1 > 0.f ? f1 : 0.f;
                float f2 = (float)ud[i] + (float)vs[i]; f2 = f2 > 0.f ? f2 : 0.f;
                a[m][i] = (bf16)(f1 + f2);
            }
        }
#pragma unroll
        for (int n = 0; n < 8; ++n) {
            bf16x8 b = ld8(W2eroT + (n * 16 + lr) * 256 + kg);
#pragma unroll
            for (int m = 0; m < 2; ++m) aro[m][n] = mfma16(a[m], b, aro[m][n]);
        }
        bf16x8 blg = ld8(W2lgT + lr * 256 + kg);
#pragma unroll
        for (int m = 0; m < 2; ++m) alg[m] = mfma16(a[m], blg, alg[m]);
    }
#pragma unroll
    for (int n = 0; n < 8; ++n) {
        int col = n * 16 + lr;
        float bia = b2ero[col];
#pragma unroll
        for (int m = 0; m < 2; ++m)
#pragma unroll
            for (int j = 0; j < 4; ++j) {
                int el = wv * 32 + m * 16 + qk * 4 + j;
                e_ro[(size_t)s_e[el] * D + col] = aro[m][n][j] + bia;
            }
    }
    if (lr < 2) {
        float bia = b2lg[lr];
#pragma unroll
        for (int m = 0; m < 2; ++m)
#pragma unroll
            for (int j = 0; j < 4; ++j) {
                int el = wv * 32 + m * 16 + qk * 4 + j;
                e_lg[(size_t)s_e[el] * 2 + lr] = alg[m][j] + bia;
            }
    }
}

// ---------------------------------------------------------------- fallback kernels (round-2 path)
__global__ void __launch_bounds__(256, 4)
edge_msg_kernel(const bf16* __restrict__ S, const bf16* __restrict__ Bm,
                const int* __restrict__ src, const int* __restrict__ dst,
                const bf16* __restrict__ We2T,
                const float* __restrict__ b_e2,
                float* __restrict__ h_out) {
    __shared__ int s_src[128];
    __shared__ int s_dst[128];
    const int t = threadIdx.x, wv = t >> 6, l = t & 63, lr = l & 15, qk = l >> 4;
    const int e0 = blockIdx.x * 128;
    if (t < 128)      s_src[t] = src[min(e0 + t, NE - 1)];
    else              s_dst[t - 128] = dst[min(e0 + t - 128, NE - 1)];
    __syncthreads();
    const bf16* pS[2];
    const bf16* pB[2];
#pragma unroll
    for (int m = 0; m < 2; ++m) {
        int el = wv * 32 + m * 16 + lr;
        pS[m] = S + s_src[el] * 256;
        pB[m] = Bm + s_dst[el] * 256;
    }
    f32x4 acc[2][8];
#pragma unroll
    for (int m = 0; m < 2; ++m)
#pragma unroll
        for (int n = 0; n < 8; ++n) acc[m][n] = 0.f;
#pragma unroll
    for (int ks = 0; ks < 8; ++ks) {
        const int kg = ks * 32 + qk * 8;
        bf16x8 a[2];
#pragma unroll
        for (int m = 0; m < 2; ++m) {
            bf16x8 sa = ld8(pS[m] + kg);
            bf16x8 sb = ld8(pB[m] + kg);
#pragma unroll
            for (int i = 0; i < 8; ++i) {
                float f = (float)sa[i] + (float)sb[i];
                a[m][i] = (bf16)(f > 0.f ? f : 0.f);
            }
        }
#pragma unroll
        for (int n = 0; n < 8; ++n) {
            bf16x8 b = ld8(We2T + (n * 16 + lr) * 256 + kg);
#pragma unroll
            for (int m = 0; m < 2; ++m) acc[m][n] = mfma16(a[m], b, acc[m][n]);
        }
    }
#pragma unroll
    for (int n = 0; n < 8; ++n) {
        int col = n * 16 + lr;
        float bia = b_e2[col];
#pragma unroll
        for (int m = 0; m < 2; ++m)
#pragma unroll
            for (int j = 0; j < 4; ++j) {
                int el = wv * 32 + m * 16 + qk * 4 + j;
                if (e0 + el < NE)
                    atomicAdd(h_out + s_dst[el] * D + col, acc[m][n][j] + bia);
            }
    }
}

__global__ void __launch_bounds__(256, 4)
edge_logit_fast(const bf16* __restrict__ U, const bf16* __restrict__ V,
                const int* __restrict__ src, const int* __restrict__ dst,
                const bf16* __restrict__ W2eroT,
                const bf16* __restrict__ W2lgT,
                const float* __restrict__ b2ero, const float* __restrict__ b2lg,
                float* __restrict__ e_ro, float* __restrict__ e_lg) {
    __shared__ int s_src[128];
    __shared__ int s_dst[128];
    const int t = threadIdx.x, wv = t >> 6, l = t & 63, lr = l & 15, qk = l >> 4;
    const int e0 = blockIdx.x * 128;
    if (t < 128)      s_src[t] = src[min(e0 + t, NE - 1)];
    else              s_dst[t - 128] = dst[min(e0 + t - 128, NE - 1)];
    __syncthreads();
    int is[2], id[2];
#pragma unroll
    for (int m = 0; m < 2; ++m) {
        int el = wv * 32 + m * 16 + lr;
        is[m] = s_src[el];
        id[m] = s_dst[el];
    }
    f32x4 aro[2][8];
    f32x4 alg[2];
#pragma unroll
    for (int m = 0; m < 2; ++m) {
        alg[m] = 0.f;
#pragma unroll
        for (int n = 0; n < 8; ++n) aro[m][n] = 0.f;
    }
#pragma unroll
    for (int ks = 0; ks < 8; ++ks) {
        const int kg = ks * 32 + qk * 8;
        bf16x8 a[2];
#pragma unroll
        for (int m = 0; m < 2; ++m) {
            bf16x8 us = ld8(U + is[m] * 256 + kg);
            bf16x8 vd = ld8(V + id[m] * 256 + kg);
            bf16x8 ud = ld8(U + id[m] * 256 + kg);
            bf16x8 vs = ld8(V + is[m] * 256 + kg);
#pragma unroll
            for (int i = 0; i < 8; ++i) {
                float f1 = (float)us[i] + (float)vd[i]; f1 = f1 > 0.f ? f1 : 0.f;
                float f2 = (float)ud[i] + (float)vs[i]; f2 = f2 > 0.f ? f2 : 0.f;
                a[m][i] = (bf16)(f1 + f2);
            }
        }
#pragma unroll
        for (int n = 0; n < 8; ++n) {
            bf16x8 b = ld8(W2eroT + (n * 16 + lr) * 256 + kg);
#pragma unroll
            for (int m = 0; m < 2; ++m) aro[m][n] = mfma16(a[m], b, aro[m][n]);
        }
        bf16x8 blg = ld8(W2lgT + lr * 256 + kg);
#pragma unroll
        for (int m = 0; m < 2; ++m) alg[m] = mfma16(a[m], blg, alg[m]);
    }
#pragma unroll
    for (int n = 0; n < 8; ++n) {
        int col = n * 16 + lr;
        float bia = b2ero[col];
#pragma unroll
        for (int m = 0; m < 2; ++m)
#pragma unroll
            for (int j = 0; j < 4; ++j) {
                int el = wv * 32 + m * 16 + qk * 4 + j;
                int e = e0 + el;
                if (e < NE) e_ro[e * D + col] = aro[m][n][j] + bia;
            }
    }
    if (lr < 2) {
        float bia = b2lg[lr];
#pragma unroll
        for (int m = 0; m < 2; ++m)
#pragma unroll
            for (int j = 0; j < 4; ++j) {
                int el = wv * 32 + m * 16 + qk * 4 + j;
                int e = e0 + el;
                if (e < NE) e_lg[e * 2 + lr] = alg[m][j] + bia;
            }
    }
}

// ---------------------------------------------------------------- n_out readout
__global__ void __launch_bounds__(256, 4)
nro_kernel(const bf16* __restrict__ nf2_bf, const bf16* __restrict__ WnroT,
           const float* __restrict__ b_nro, float* __restrict__ n_out) {
    const int r0 = blockIdx.x * 64;
    const int t = threadIdx.x, wv = t >> 6, l = t & 63, lr = l & 15, qk = l >> 4;
    int row[4];
#pragma unroll
    for (int m = 0; m < 4; ++m) { int r = r0 + m * 16 + lr; row[m] = r < NN ? r : NN - 1; }
    int col2[2];
#pragma unroll
    for (int n = 0; n < 2; ++n) col2[n] = wv * 32 + n * 16 + lr;
    f32x4 acc[4][2];
#pragma unroll
    for (int m = 0; m < 4; ++m)
#pragma unroll
        for (int n = 0; n < 2; ++n) acc[m][n] = 0.f;
#pragma unroll
    for (int ks = 0; ks < 4; ++ks) {
        const int kg = ks * 32 + qk * 8;
        bf16x8 a[4], b[2];
#pragma unroll
        for (int m = 0; m < 4; ++m) a[m] = ld8(nf2_bf + (size_t)row[m] * D + kg);
#pragma unroll
        for (int n = 0; n < 2; ++n) b[n] = ld8(WnroT + col2[n] * 128 + kg);
#pragma unroll
        for (int m = 0; m < 4; ++m)
#pragma unroll
            for (int n = 0; n < 2; ++n) acc[m][n] = mfma16(a[m], b[n], acc[m][n]);
    }
#pragma unroll
    for (int n = 0; n < 2; ++n) {
        float bia = b_nro[col2[n]];
#pragma unroll
        for (int m = 0; m < 4; ++m)
#pragma unroll
            for (int j = 0; j < 4; ++j) {
                int gr = r0 + m * 16 + qk * 4 + j;
                if (gr < NN) n_out[(size_t)gr * D + col2[n]] = acc[m][n][j] + bia;
            }
    }
}

// ---------------------------------------------------------------- launch
extern "C" void kernel_launch(void* const* d_in, const int* in_sizes, int n_in,
                              void* d_out, int out_size, void* d_ws, size_t ws_size,
                              hipStream_t stream) {
    const float* node_feat = (const float*)d_in[0];
    const int*   src   = (const int*)d_in[1];
    const int*   dst   = (const int*)d_in[2];
    const float* W_e1  = (const float*)d_in[3];
    const float* b_e1  = (const float*)d_in[4];
    const float* W_e2  = (const float*)d_in[5];
    const float* b_e2  = (const float*)d_in[6];
    const float* W_n1  = (const float*)d_in[7];
    const float* b_n1  = (const float*)d_in[8];
    const float* W_n2  = (const float*)d_in[9];
    const float* b_n2  = (const float*)d_in[10];
    const float* W_el1 = (const float*)d_in[11];
    const float* b_el1 = (const float*)d_in[12];
    const float* W_el2 = (const float*)d_in[13];
    const float* b_el2 = (const float*)d_in[14];
    const float* W_logit = (const float*)d_in[15];
    const float* b_logit = (const float*)d_in[16];
    const float* W_nro = (const float*)d_in[17];
    const float* b_nro = (const float*)d_in[18];
    const float* W_ero = (const float*)d_in[19];
    const float* b_ero = (const float*)d_in[20];

    char* ws = (char*)d_ws;
    bf16* wb = (bf16*)ws;
    bf16* WmbT   = wb;            // [512][128]
    bf16* WtopT  = wb + 65536;    // [256][128]
    bf16* We2T   = wb + 98304;    // [128][256]
    bf16* Wn1T   = wb + 131072;   // [256][256]
    bf16* Wn2T   = wb + 196608;   // [128][256]
    bf16* WuvT   = wb + 229376;   // [512][128]
    bf16* WnroT  = wb + 294912;   // [128][128]
    bf16* W2eroT = wb + 311296;   // [128][256]
    bf16* W2lgT  = wb + 344064;   // [16][256]
    float* fb    = (float*)(ws + 928000);
    float* b2ero = fb;
    float* b2lg  = fb + 128;

    float* out   = (float*)d_out;
    float* n_out = out;                 // NN*128 f32 (15.36 MB)
    float* e_ro  = out + 3840000;       // NE*128 f32 (307.2 MB)
    float* e_lg  = out + 80640000;      // NE*2 f32 (4.8 MB)

    TPack pk;
    pk.m[0]  = {W_e1 + 128 * 256, WmbT,              128, 256};
    pk.m[1]  = {W_e1 + 256 * 256, WmbT + 256 * 128,  128, 256};
    pk.m[2]  = {W_e1,             WtopT,             128, 256};
    pk.m[3]  = {W_e2,             We2T,              256, 128};
    pk.m[4]  = {W_n1,             Wn1T,              256, 256};
    pk.m[5]  = {W_n2,             Wn2T,              256, 128};
    pk.m[6]  = {W_el1,            WuvT,              128, 256};
    pk.m[7]  = {W_el1 + 128 * 256, WuvT + 256 * 128, 128, 256};
    pk.m[8]  = {W_nro,            WnroT,             128, 128};
    pk.m[9]  = {W_nro,            WnroT,             128, 128};
    pk.m[10] = {W_nro,            WnroT,             128, 128};
    pk.m[11] = {W_nro,            WnroT,             128, 128};

    const size_t NEED_NEW = 28888576;

    if (ws_size >= NEED_NEW) {
        // ---------------- dst-sorted CSR, atomic-free ----------------
        char* eb = (char*)e_ro;   // 307.2 MB of dead-until-logit space
        bf16* S    = (bf16*)(eb);
        bf16* Bm   = (bf16*)(eb + 15360000);
        bf16* T    = (bf16*)(eb + 30720000);
        bf16* h1   = (bf16*)(eb + 46080000);
        bf16* h2   = (bf16*)(eb + 53760000);
        int* counts  = (int*)(eb + 61440000);
        int* offsets = (int*)(eb + 61560000);
        int* cursor  = (int*)(eb + 61680004);
        bf16* U    = (bf16*)n_out;           // dead until nro (runs last)
        bf16* nf2_bf = (bf16*)(ws + 1048576);
        bf16* Vbuf   = (bf16*)(ws + 8728576);
        int*  perm   = (int*)(ws + 24088576);
        u16*  srcS   = (u16*)(ws + 26488576);
        u16*  dstS   = (u16*)(ws + 27688576);

        transpose_cast_kernel<<<dim3(12, 40), 256, 0, stream>>>(pk);
        fuse_kernel<<<257, 160, 0, stream>>>(W_el2, W_ero, W_logit, b_el2, b_ero, b_logit,
                                             W2eroT, W2lgT, b2ero, b2lg);
        hipMemsetAsync(counts, 0, NN * 4, stream);
        hist_kernel<<<(NE + 255) / 256, 256, 0, stream>>>(dst, counts);
        scan_kernel<<<1, 1024, 0, stream>>>(counts, offsets, cursor);
        scatter_kernel<<<(NE + 255) / 256, 256, 0, stream>>>(src, dst, cursor,
                                                             perm, srcS, dstS);
        node_pre_kernel<false><<<dim3(469, 2), 256, 0, stream>>>(
            node_feat, nullptr, WmbT, b_e1, S, Bm);
        seg_sum_kernel<<<7500, 256, 0, stream>>>(S, Bm, offsets, srcS, T);
        h_gemm_kernel<<<469, 256, 0, stream>>>(T, We2T, b_e2, counts, h1);
        s2_update_kernel<true><<<469, 256, 0, stream>>>(h1, WtopT, S);
        seg_sum_kernel<<<7500, 256, 0, stream>>>(S, Bm, offsets, srcS, T);
        h_gemm_kernel<<<469, 256, 0, stream>>>(T, We2T, b_e2, counts, h2);
        node_mlp_kernel<true><<<469, 256, 0, stream>>>(
            node_feat, h2, Wn1T, Wn2T, b_n1, b_n2, nf2_bf);
        node_pre_kernel<true><<<dim3(469, 2), 256, 0, stream>>>(
            nullptr, nf2_bf, WuvT, b_el1, U, Vbuf);
        edge_logit_sorted<<<4688, 256, 0, stream>>>(
            U, Vbuf, perm, srcS, dstS, W2eroT, W2lgT, b2ero, b2lg, e_ro, e_lg);
        nro_kernel<<<469, 256, 0, stream>>>(nf2_bf, WnroT, b_nro, n_out);
    } else {
        // ---------------- fallback: round-2 proven path ----------------
        bf16* nf2_bf = (bf16*)(ws + 1048576);
        bf16* Vbuf   = (bf16*)(ws + 9000000);
        float* h1f = n_out;
        bf16*  S   = (bf16*)e_ro;
        bf16*  Bm  = (bf16*)((char*)e_ro + 15360000);
        float* h2f = (float*)((char*)e_ro + 30720000);
        bf16*  U   = (bf16*)n_out;

        transpose_cast_kernel<<<dim3(12, 40), 256, 0, stream>>>(pk);
        fuse_kernel<<<257, 160, 0, stream>>>(W_el2, W_ero, W_logit, b_el2, b_ero, b_logit,
                                             W2eroT, W2lgT, b2ero, b2lg);
        hipMemsetAsync(h1f, 0, (size_t)NN * D * 4, stream);
        hipMemsetAsync(h2f, 0, (size_t)NN * D * 4, stream);
        node_pre_kernel<false><<<dim3(469, 2), 256, 0, stream>>>(
            node_feat, nullptr, WmbT, b_e1, S, Bm);
        edge_msg_kernel<<<4688, 256, 0, stream>>>(S, Bm, src, dst, We2T, b_e2, h1f);
        s2_update_kernel<false><<<469, 256, 0, stream>>>(h1f, WtopT, S);
        edge_msg_kernel<<<4688, 256, 0, stream>>>(S, Bm, src, dst, We2T, b_e2, h2f);
        node_mlp_kernel<false><<<469, 256, 0, stream>>>(
            node_feat, h2f, Wn1T, Wn2T, b_n1, b_n2, nf2_bf);
        node_pre_kernel<true><<<dim3(469, 2), 256, 0, stream>>>(
            nullptr, nf2_bf, WuvT, b_el1, U, Vbuf);
        edge_logit_fast<<<4688, 256, 0, stream>>>(
            U, Vbuf, src, dst, W2eroT, W2lgT, b2ero, b2lg, e_ro, e_lg);
        nro_kernel<<<469, 256, 0, stream>>>(nf2_bf, WnroT, b_nro, n_out);
    }
}

// Round 9
// 735.659 us; speedup vs baseline: 2.3610x; 1.0252x over previous
//
#include <hip/hip_runtime.h>
#include <hip/hip_bf16.h>

typedef __bf16 bf16;
typedef unsigned short u16;
typedef bf16 bf16x8 __attribute__((ext_vector_type(8)));
typedef bf16 bf16x4 __attribute__((ext_vector_type(4)));
typedef float f32x4 __attribute__((ext_vector_type(4)));

constexpr int NN = 30000;
constexpr int NE = 600000;
constexpr int D  = 128;

__device__ inline f32x4 mfma16(bf16x8 a, bf16x8 b, f32x4 c) {
    return __builtin_amdgcn_mfma_f32_16x16x32_bf16(a, b, c, 0, 0, 0);
}
__device__ inline bf16x8 ld8(const bf16* p) {
    return *reinterpret_cast<const bf16x8*>(p);
}
__device__ inline bf16x8 cvt8(const float* p) {
    float4 v0 = reinterpret_cast<const float4*>(p)[0];
    float4 v1 = reinterpret_cast<const float4*>(p)[1];
    bf16x8 r;
    r[0] = (bf16)v0.x; r[1] = (bf16)v0.y; r[2] = (bf16)v0.z; r[3] = (bf16)v0.w;
    r[4] = (bf16)v1.x; r[5] = (bf16)v1.y; r[6] = (bf16)v1.z; r[7] = (bf16)v1.w;
    return r;
}
__device__ inline int swz512(int row, int byteInRow) {
    return row * 512 + (byteInRow ^ ((row & 15) << 4));
}

// ---------------------------------------------------------------- prep
struct TMat { const float* src; bf16* dst; int K; int Nc; };
struct TPack { TMat m[12]; };

__global__ void transpose_cast_kernel(TPack p) {
    TMat mm = p.m[blockIdx.x];
    int total = mm.K * mm.Nc;
    for (int idx = blockIdx.y * blockDim.x + threadIdx.x; idx < total;
         idx += gridDim.y * blockDim.x) {
        int c = idx / mm.K;
        int k = idx - c * mm.K;
        mm.dst[idx] = (bf16)mm.src[k * mm.Nc + c];
    }
}

__global__ void fuse_kernel(const float* __restrict__ W_el2,
                            const float* __restrict__ W_ero,
                            const float* __restrict__ W_logit,
                            const float* __restrict__ b_el2,
                            const float* __restrict__ b_ero,
                            const float* __restrict__ b_logit,
                            bf16* __restrict__ W2eroT, bf16* __restrict__ W2lgT,
                            float* __restrict__ b2ero, float* __restrict__ b2lg) {
    int k = blockIdx.x;
    int c = threadIdx.x;
    if (c >= 144) return;
    if (k < 256) {
        if (c < 128) {
            float s = 0.f;
            for (int j = 0; j < 128; ++j) s += W_el2[k * 128 + j] * W_ero[j * 128 + c];
            W2eroT[c * 256 + k] = (bf16)s;
        } else {
            int cc = c - 128;
            float s = 0.f;
            if (cc < 2) for (int j = 0; j < 128; ++j) s += W_el2[k * 128 + j] * W_logit[j * 2 + cc];
            W2lgT[cc * 256 + k] = (bf16)s;
        }
    } else {
        if (c < 128) {
            float s = b_ero[c];
            for (int j = 0; j < 128; ++j) s += 2.f * b_el2[j] * W_ero[j * 128 + c];
            b2ero[c] = s;
        } else if (c < 130) {
            int cc = c - 128;
            float s = b_logit[cc];
            for (int j = 0; j < 128; ++j) s += 2.f * b_el2[j] * W_logit[j * 2 + cc];
            b2lg[cc] = s;
        }
    }
}

// Wcs = W_e2 @ W_e1[0:128]  (for S-update);  Wcn = W_e2 @ W_n1[128:256] (for node MLP)
__global__ void fuse2_kernel(const float* __restrict__ W_e2,
                             const float* __restrict__ W_e1,
                             const float* __restrict__ W_n1,
                             const float* __restrict__ b_e2,
                             bf16* __restrict__ WcsT, bf16* __restrict__ WcnT,
                             float* __restrict__ bcs, float* __restrict__ bcn) {
    int k = blockIdx.x;     // 0..255 weight rows, 256 = bias row
    int c = threadIdx.x;    // 0..255 output col
    if (k < 256) {
        float s1 = 0.f, s2 = 0.f;
        for (int j = 0; j < 128; ++j) {
            float w = W_e2[k * 128 + j];
            s1 += w * W_e1[j * 256 + c];
            s2 += w * W_n1[(128 + j) * 256 + c];
        }
        WcsT[c * 256 + k] = (bf16)s1;
        WcnT[c * 256 + k] = (bf16)s2;
    } else {
        float s1 = 0.f, s2 = 0.f;
        for (int j = 0; j < 128; ++j) {
            float b = b_e2[j];
            s1 += b * W_e1[j * 256 + c];
            s2 += b * W_n1[(128 + j) * 256 + c];
        }
        bcs[c] = s1;
        bcn[c] = s2;
    }
}

// ---------------------------------------------------------------- sort (counting sort by dst)
__global__ void hist_kernel(const int* __restrict__ dst, int* __restrict__ counts) {
    int e = blockIdx.x * blockDim.x + threadIdx.x;
    if (e < NE) atomicAdd(counts + dst[e], 1);
}

__global__ void scan_kernel(const int* __restrict__ counts, int* __restrict__ offsets,
                            int* __restrict__ cursor) {
    __shared__ int part[1024];
    const int t = threadIdx.x;
    const int base = t * 30;
    int local[30];
    int s = 0;
#pragma unroll
    for (int i = 0; i < 30; ++i) {
        int idx = base + i;
        int v = (idx < NN) ? counts[idx] : 0;
        local[i] = s;
        s += v;
    }
    part[t] = s;
    __syncthreads();
    for (int off = 1; off < 1024; off <<= 1) {
        int x = (t >= off) ? part[t - off] : 0;
        __syncthreads();
        part[t] += x;
        __syncthreads();
    }
    int chunkExcl = (t == 0) ? 0 : part[t - 1];
#pragma unroll
    for (int i = 0; i < 30; ++i) {
        int idx = base + i;
        if (idx < NN) {
            int excl = chunkExcl + local[i];
            offsets[idx] = excl;
            cursor[idx] = excl;
        }
    }
    if (t == 0) offsets[NN] = NE;
}

__global__ void scatter_kernel(const int* __restrict__ src, const int* __restrict__ dst,
                               int* __restrict__ cursor, int* __restrict__ perm,
                               u16* __restrict__ srcS, u16* __restrict__ dstS) {
    int e = blockIdx.x * blockDim.x + threadIdx.x;
    if (e < NE) {
        int d = dst[e];
        int p = atomicAdd(cursor + d, 1);
        perm[p] = e;
        srcS[p] = (u16)src[e];
        dstS[p] = (u16)d;
    }
}

// ---------------------------------------------------------------- node-level GEMMs
template<bool IN_BF16>
__global__ void __launch_bounds__(256, 4)
node_pre_kernel(const float* __restrict__ inF, const bf16* __restrict__ inB,
                const bf16* __restrict__ WT,       // [512][128]
                const float* __restrict__ bias0,
                bf16* __restrict__ O1, bf16* __restrict__ O2) {
    const int half = blockIdx.y;
    const int r0 = blockIdx.x * 64;
    const int t = threadIdx.x, wv = t >> 6, l = t & 63, lr = l & 15, qk = l >> 4;
    int row[4];
#pragma unroll
    for (int m = 0; m < 4; ++m) { int r = r0 + m * 16 + lr; row[m] = r < NN ? r : NN - 1; }
    int coln[4];
#pragma unroll
    for (int n = 0; n < 4; ++n) coln[n] = wv * 64 + n * 16 + lr;
    f32x4 acc[4][4];
#pragma unroll
    for (int m = 0; m < 4; ++m)
#pragma unroll
        for (int n = 0; n < 4; ++n) acc[m][n] = 0.f;
#pragma unroll
    for (int ks = 0; ks < 4; ++ks) {
        const int kg = ks * 32 + qk * 8;
        bf16x8 a[4], b[4];
#pragma unroll
        for (int m = 0; m < 4; ++m)
            a[m] = IN_BF16 ? ld8(inB + row[m] * D + kg) : cvt8(inF + row[m] * D + kg);
#pragma unroll
        for (int n = 0; n < 4; ++n) b[n] = ld8(WT + (half * 256 + coln[n]) * 128 + kg);
#pragma unroll
        for (int m = 0; m < 4; ++m)
#pragma unroll
            for (int n = 0; n < 4; ++n) acc[m][n] = mfma16(a[m], b[n], acc[m][n]);
    }
    bf16* O = half ? O2 : O1;
#pragma unroll
    for (int n = 0; n < 4; ++n) {
        float bia = (half == 0 && bias0) ? bias0[coln[n]] : 0.f;
#pragma unroll
        for (int m = 0; m < 4; ++m)
#pragma unroll
            for (int j = 0; j < 4; ++j) {
                int gr = r0 + m * 16 + qk * 4 + j;
                if (gr < NN) O[gr * 256 + coln[n]] = (bf16)(acc[m][n][j] + bia);
            }
    }
}

// S[r][c] += T[r] @ WcsT[c] + deg[r]*bcs[c]   (K=256, fused e2+top)
__global__ void __launch_bounds__(256, 4)
s2_fused_kernel(const bf16* __restrict__ T, const bf16* __restrict__ WcsT,
                const float* __restrict__ bcs, const int* __restrict__ deg,
                bf16* __restrict__ S) {
    const int r0 = blockIdx.x * 64;
    const int t = threadIdx.x, wv = t >> 6, l = t & 63, lr = l & 15, qk = l >> 4;
    int row[4];
#pragma unroll
    for (int m = 0; m < 4; ++m) { int r = r0 + m * 16 + lr; row[m] = r < NN ? r : NN - 1; }
    int coln[4];
#pragma unroll
    for (int n = 0; n < 4; ++n) coln[n] = wv * 64 + n * 16 + lr;
    f32x4 acc[4][4];
#pragma unroll
    for (int m = 0; m < 4; ++m)
#pragma unroll
        for (int n = 0; n < 4; ++n) acc[m][n] = 0.f;
#pragma unroll
    for (int ks = 0; ks < 8; ++ks) {
        const int kg = ks * 32 + qk * 8;
        bf16x8 a[4], b[4];
#pragma unroll
        for (int m = 0; m < 4; ++m) a[m] = ld8(T + (size_t)row[m] * 256 + kg);
#pragma unroll
        for (int n = 0; n < 4; ++n) b[n] = ld8(WcsT + coln[n] * 256 + kg);
#pragma unroll
        for (int m = 0; m < 4; ++m)
#pragma unroll
            for (int n = 0; n < 4; ++n) acc[m][n] = mfma16(a[m], b[n], acc[m][n]);
    }
#pragma unroll
    for (int n = 0; n < 4; ++n) {
        float bw = bcs[coln[n]];
#pragma unroll
        for (int m = 0; m < 4; ++m)
#pragma unroll
            for (int j = 0; j < 4; ++j) {
                int gr = r0 + m * 16 + qk * 4 + j;
                if (gr < NN) {
                    int idx = gr * 256 + coln[n];
                    S[idx] = (bf16)((float)S[idx] + acc[m][n][j] + (float)deg[gr] * bw);
                }
            }
    }
}

// fallback-path S update: S += h1 @ WtopT (K=128, h fp32)
__global__ void __launch_bounds__(256, 4)
s2_update_kernel(const float* __restrict__ h1, const bf16* __restrict__ WtopT,
                 bf16* __restrict__ S) {
    const int r0 = blockIdx.x * 64;
    const int t = threadIdx.x, wv = t >> 6, l = t & 63, lr = l & 15, qk = l >> 4;
    int row[4];
#pragma unroll
    for (int m = 0; m < 4; ++m) { int r = r0 + m * 16 + lr; row[m] = r < NN ? r : NN - 1; }
    int coln[4];
#pragma unroll
    for (int n = 0; n < 4; ++n) coln[n] = wv * 64 + n * 16 + lr;
    f32x4 acc[4][4];
#pragma unroll
    for (int m = 0; m < 4; ++m)
#pragma unroll
        for (int n = 0; n < 4; ++n) acc[m][n] = 0.f;
#pragma unroll
    for (int ks = 0; ks < 4; ++ks) {
        const int kg = ks * 32 + qk * 8;
        bf16x8 a[4], b[4];
#pragma unroll
        for (int m = 0; m < 4; ++m) a[m] = cvt8(h1 + (size_t)row[m] * D + kg);
#pragma unroll
        for (int n = 0; n < 4; ++n) b[n] = ld8(WtopT + coln[n] * 128 + kg);
#pragma unroll
        for (int m = 0; m < 4; ++m)
#pragma unroll
            for (int n = 0; n < 4; ++n) acc[m][n] = mfma16(a[m], b[n], acc[m][n]);
    }
#pragma unroll
    for (int n = 0; n < 4; ++n)
#pragma unroll
        for (int m = 0; m < 4; ++m)
#pragma unroll
            for (int j = 0; j < 4; ++j) {
                int gr = r0 + m * 16 + qk * 4 + j;
                if (gr < NN) {
                    int idx = gr * 256 + coln[n];
                    S[idx] = (bf16)((float)S[idx] + acc[m][n][j]);
                }
            }
}

// ---------------------------------------------------------------- segment sum (one wave per dst)
__global__ void __launch_bounds__(256, 8)
seg_sum_kernel(const bf16* __restrict__ S, const bf16* __restrict__ Bm,
               const int* __restrict__ offsets, const u16* __restrict__ srcS,
               bf16* __restrict__ T) {
    const int gw = (blockIdx.x * blockDim.x + threadIdx.x) >> 6;
    if (gw >= NN) return;
    const int l = threadIdx.x & 63;
    const int beg = offsets[gw], end = offsets[gw + 1];
    bf16x4 bv = *reinterpret_cast<const bf16x4*>(Bm + (size_t)gw * 256 + l * 4);
    const float b0 = (float)bv[0], b1 = (float)bv[1], b2 = (float)bv[2], b3 = (float)bv[3];
    float t0 = 0.f, t1 = 0.f, t2 = 0.f, t3 = 0.f;
    int i = beg;
    for (; i + 4 <= end; i += 4) {
        int s0 = srcS[i], s1 = srcS[i + 1], s2 = srcS[i + 2], s3 = srcS[i + 3];
        bf16x4 a0 = *reinterpret_cast<const bf16x4*>(S + (size_t)s0 * 256 + l * 4);
        bf16x4 a1 = *reinterpret_cast<const bf16x4*>(S + (size_t)s1 * 256 + l * 4);
        bf16x4 a2 = *reinterpret_cast<const bf16x4*>(S + (size_t)s2 * 256 + l * 4);
        bf16x4 a3 = *reinterpret_cast<const bf16x4*>(S + (size_t)s3 * 256 + l * 4);
        float v;
        v = (float)a0[0] + b0; t0 += v > 0.f ? v : 0.f;
        v = (float)a0[1] + b1; t1 += v > 0.f ? v : 0.f;
        v = (float)a0[2] + b2; t2 += v > 0.f ? v : 0.f;
        v = (float)a0[3] + b3; t3 += v > 0.f ? v : 0.f;
        v = (float)a1[0] + b0; t0 += v > 0.f ? v : 0.f;
        v = (float)a1[1] + b1; t1 += v > 0.f ? v : 0.f;
        v = (float)a1[2] + b2; t2 += v > 0.f ? v : 0.f;
        v = (float)a1[3] + b3; t3 += v > 0.f ? v : 0.f;
        v = (float)a2[0] + b0; t0 += v > 0.f ? v : 0.f;
        v = (float)a2[1] + b1; t1 += v > 0.f ? v : 0.f;
        v = (float)a2[2] + b2; t2 += v > 0.f ? v : 0.f;
        v = (float)a2[3] + b3; t3 += v > 0.f ? v : 0.f;
        v = (float)a3[0] + b0; t0 += v > 0.f ? v : 0.f;
        v = (float)a3[1] + b1; t1 += v > 0.f ? v : 0.f;
        v = (float)a3[2] + b2; t2 += v > 0.f ? v : 0.f;
        v = (float)a3[3] + b3; t3 += v > 0.f ? v : 0.f;
    }
    for (; i < end; ++i) {
        int s0 = srcS[i];
        bf16x4 a0 = *reinterpret_cast<const bf16x4*>(S + (size_t)s0 * 256 + l * 4);
        float v;
        v = (float)a0[0] + b0; t0 += v > 0.f ? v : 0.f;
        v = (float)a0[1] + b1; t1 += v > 0.f ? v : 0.f;
        v = (float)a0[2] + b2; t2 += v > 0.f ? v : 0.f;
        v = (float)a0[3] + b3; t3 += v > 0.f ? v : 0.f;
    }
    bf16x4 o;
    o[0] = (bf16)t0; o[1] = (bf16)t1; o[2] = (bf16)t2; o[3] = (bf16)t3;
    *reinterpret_cast<bf16x4*>(T + (size_t)gw * 256 + l * 4) = o;
}

// ---------------------------------------------------------------- node MLP (fused h: uses T2, K=256)
__global__ void __launch_bounds__(256, 2)
node_mlp_fused(const float* __restrict__ node_feat,
               const bf16* __restrict__ T2,
               const bf16* __restrict__ Wn1T,    // [256][256] (k<128 = nf part)
               const bf16* __restrict__ WcnT,    // [256][256]
               const bf16* __restrict__ Wn2T,
               const float* __restrict__ b_n1,
               const float* __restrict__ bcn,
               const int* __restrict__ deg,
               const float* __restrict__ b_n2,
               bf16* __restrict__ nf2_bf) {
    __shared__ __align__(16) char sH[64 * 512];
    const int t = threadIdx.x, wv = t >> 6, l = t & 63, lr = l & 15, qk = l >> 4;
    const int r0 = blockIdx.x * 64;
    int row[4];
#pragma unroll
    for (int m = 0; m < 4; ++m) { int r = r0 + m * 16 + lr; row[m] = r < NN ? r : NN - 1; }
    int coln[4];
#pragma unroll
    for (int n = 0; n < 4; ++n) coln[n] = wv * 64 + n * 16 + lr;
    f32x4 acc[4][4];
#pragma unroll
    for (int m = 0; m < 4; ++m)
#pragma unroll
        for (int n = 0; n < 4; ++n) acc[m][n] = 0.f;
    // nf part, K=128
#pragma unroll
    for (int ks = 0; ks < 4; ++ks) {
        const int kg = ks * 32 + qk * 8;
        bf16x8 a[4], b[4];
#pragma unroll
        for (int m = 0; m < 4; ++m) a[m] = cvt8(node_feat + (size_t)row[m] * D + kg);
#pragma unroll
        for (int n = 0; n < 4; ++n) b[n] = ld8(Wn1T + coln[n] * 256 + kg);
#pragma unroll
        for (int m = 0; m < 4; ++m)
#pragma unroll
            for (int n = 0; n < 4; ++n) acc[m][n] = mfma16(a[m], b[n], acc[m][n]);
    }
    // fused h part: T2 @ Wcn, K=256
#pragma unroll
    for (int ks = 0; ks < 8; ++ks) {
        const int kg = ks * 32 + qk * 8;
        bf16x8 a[4], b[4];
#pragma unroll
        for (int m = 0; m < 4; ++m) a[m] = ld8(T2 + (size_t)row[m] * 256 + kg);
#pragma unroll
        for (int n = 0; n < 4; ++n) b[n] = ld8(WcnT + coln[n] * 256 + kg);
#pragma unroll
        for (int m = 0; m < 4; ++m)
#pragma unroll
            for (int n = 0; n < 4; ++n) acc[m][n] = mfma16(a[m], b[n], acc[m][n]);
    }
#pragma unroll
    for (int n = 0; n < 4; ++n) {
        float bia = b_n1[coln[n]];
        float bw  = bcn[coln[n]];
#pragma unroll
        for (int m = 0; m < 4; ++m)
#pragma unroll
            for (int j = 0; j < 4; ++j) {
                int r = m * 16 + qk * 4 + j;
                int gr = r0 + r;
                float dg = (gr < NN) ? (float)deg[gr] : 0.f;
                float v = acc[m][n][j] + bia + dg * bw;
                v = v > 0.f ? v : 0.f;
                *reinterpret_cast<bf16*>(sH + swz512(r, coln[n] * 2)) = (bf16)v;
            }
    }
    __syncthreads();
    int col2[2];
#pragma unroll
    for (int n = 0; n < 2; ++n) col2[n] = wv * 32 + n * 16 + lr;
    f32x4 acc2[4][2];
#pragma unroll
    for (int m = 0; m < 4; ++m)
#pragma unroll
        for (int n = 0; n < 2; ++n) acc2[m][n] = 0.f;
#pragma unroll
    for (int ks = 0; ks < 8; ++ks) {
        const int k0 = ks * 32 + qk * 8;
        bf16x8 a[4], b[2];
#pragma unroll
        for (int m = 0; m < 4; ++m)
            a[m] = *reinterpret_cast<const bf16x8*>(sH + swz512(m * 16 + lr, k0 * 2));
#pragma unroll
        for (int n = 0; n < 2; ++n) b[n] = ld8(Wn2T + col2[n] * 256 + k0);
#pragma unroll
        for (int m = 0; m < 4; ++m)
#pragma unroll
            for (int n = 0; n < 2; ++n) acc2[m][n] = mfma16(a[m], b[n], acc2[m][n]);
    }
#pragma unroll
    for (int n = 0; n < 2; ++n) {
        float bia = b_n2[col2[n]];
#pragma unroll
        for (int m = 0; m < 4; ++m)
#pragma unroll
            for (int j = 0; j < 4; ++j) {
                int gr = r0 + m * 16 + qk * 4 + j;
                if (gr < NN) nf2_bf[(size_t)gr * D + col2[n]] = (bf16)(acc2[m][n][j] + bia);
            }
    }
}

// fallback node MLP (h fp32, K=128 each)
__global__ void __launch_bounds__(256, 2)
node_mlp_kernel(const float* __restrict__ node_feat,
                const float* __restrict__ h2,
                const bf16* __restrict__ Wn1T,
                const bf16* __restrict__ Wn2T,
                const float* __restrict__ b_n1,
                const float* __restrict__ b_n2,
                bf16* __restrict__ nf2_bf) {
    __shared__ __align__(16) char sH[64 * 512];
    const int t = threadIdx.x, wv = t >> 6, l = t & 63, lr = l & 15, qk = l >> 4;
    const int r0 = blockIdx.x * 64;
    int row[4];
#pragma unroll
    for (int m = 0; m < 4; ++m) { int r = r0 + m * 16 + lr; row[m] = r < NN ? r : NN - 1; }
    int coln[4];
#pragma unroll
    for (int n = 0; n < 4; ++n) coln[n] = wv * 64 + n * 16 + lr;
    f32x4 acc[4][4];
#pragma unroll
    for (int m = 0; m < 4; ++m)
#pragma unroll
        for (int n = 0; n < 4; ++n) acc[m][n] = 0.f;
#pragma unroll
    for (int ks = 0; ks < 4; ++ks) {
        const int kg = ks * 32 + qk * 8;
        bf16x8 a[4], b[4];
#pragma unroll
        for (int m = 0; m < 4; ++m) a[m] = cvt8(node_feat + (size_t)row[m] * D + kg);
#pragma unroll
        for (int n = 0; n < 4; ++n) b[n] = ld8(Wn1T + coln[n] * 256 + kg);
#pragma unroll
        for (int m = 0; m < 4; ++m)
#pragma unroll
            for (int n = 0; n < 4; ++n) acc[m][n] = mfma16(a[m], b[n], acc[m][n]);
#pragma unroll
        for (int m = 0; m < 4; ++m) a[m] = cvt8(h2 + (size_t)row[m] * D + kg);
#pragma unroll
        for (int n = 0; n < 4; ++n) b[n] = ld8(Wn1T + coln[n] * 256 + 128 + kg);
#pragma unroll
        for (int m = 0; m < 4; ++m)
#pragma unroll
            for (int n = 0; n < 4; ++n) acc[m][n] = mfma16(a[m], b[n], acc[m][n]);
    }
#pragma unroll
    for (int n = 0; n < 4; ++n) {
        float bia = b_n1[coln[n]];
#pragma unroll
        for (int m = 0; m < 4; ++m)
#pragma unroll
            for (int j = 0; j < 4; ++j) {
                int r = m * 16 + qk * 4 + j;
                float v = acc[m][n][j] + bia;
                v = v > 0.f ? v : 0.f;
                *reinterpret_cast<bf16*>(sH + swz512(r, coln[n] * 2)) = (bf16)v;
            }
    }
    __syncthreads();
    int col2[2];
#pragma unroll
    for (int n = 0; n < 2; ++n) col2[n] = wv * 32 + n * 16 + lr;
    f32x4 acc2[4][2];
#pragma unroll
    for (int m = 0; m < 4; ++m)
#pragma unroll
        for (int n = 0; n < 2; ++n) acc2[m][n] = 0.f;
#pragma unroll
    for (int ks = 0; ks < 8; ++ks) {
        const int k0 = ks * 32 + qk * 8;
        bf16x8 a[4], b[2];
#pragma unroll
        for (int m = 0; m < 4; ++m)
            a[m] = *reinterpret_cast<const bf16x8*>(sH + swz512(m * 16 + lr, k0 * 2));
#pragma unroll
        for (int n = 0; n < 2; ++n) b[n] = ld8(Wn2T + col2[n] * 256 + k0);
#pragma unroll
        for (int m = 0; m < 4; ++m)
#pragma unroll
            for (int n = 0; n < 2; ++n) acc2[m][n] = mfma16(a[m], b[n], acc2[m][n]);
    }
#pragma unroll
    for (int n = 0; n < 2; ++n) {
        float bia = b_n2[col2[n]];
#pragma unroll
        for (int m = 0; m < 4; ++m)
#pragma unroll
            for (int j = 0; j < 4; ++j) {
                int gr = r0 + m * 16 + qk * 4 + j;
                if (gr < NN) nf2_bf[(size_t)gr * D + col2[n]] = (bf16)(acc2[m][n][j] + bia);
            }
    }
}

// h[r] = T[r] @ We2T + deg[r]*b_e2 (fallback only)
__global__ void __launch_bounds__(256, 4)
h_gemm_kernel(const bf16* __restrict__ T, const bf16* __restrict__ We2T,
              const float* __restrict__ b_e2, const int* __restrict__ deg,
              bf16* __restrict__ h) {
    const int r0 = blockIdx.x * 64;
    const int t = threadIdx.x, wv = t >> 6, l = t & 63, lr = l & 15, qk = l >> 4;
    int row[4];
#pragma unroll
    for (int m = 0; m < 4; ++m) { int r = r0 + m * 16 + lr; row[m] = r < NN ? r : NN - 1; }
    int col2[2];
#pragma unroll
    for (int n = 0; n < 2; ++n) col2[n] = wv * 32 + n * 16 + lr;
    f32x4 acc[4][2];
#pragma unroll
    for (int m = 0; m < 4; ++m)
#pragma unroll
        for (int n = 0; n < 2; ++n) acc[m][n] = 0.f;
#pragma unroll
    for (int ks = 0; ks < 8; ++ks) {
        const int kg = ks * 32 + qk * 8;
        bf16x8 a[4], b[2];
#pragma unroll
        for (int m = 0; m < 4; ++m) a[m] = ld8(T + (size_t)row[m] * 256 + kg);
#pragma unroll
        for (int n = 0; n < 2; ++n) b[n] = ld8(We2T + col2[n] * 256 + kg);
#pragma unroll
        for (int m = 0; m < 4; ++m)
#pragma unroll
            for (int n = 0; n < 2; ++n) acc[m][n] = mfma16(a[m], b[n], acc[m][n]);
    }
#pragma unroll
    for (int n = 0; n < 2; ++n) {
        float bw = b_e2[col2[n]];
#pragma unroll
        for (int m = 0; m < 4; ++m)
#pragma unroll
            for (int j = 0; j < 4; ++j) {
                int gr = r0 + m * 16 + qk * 4 + j;
                if (gr < NN)
                    h[(size_t)gr * D + col2[n]] = (bf16)(acc[m][n][j] + (float)deg[gr] * bw);
            }
    }
}

// ---------------------------------------------------------------- edge logits (dst-sorted)
// r7 config + NONTEMPORAL e_ro stores (keep write stream out of L2/L3 -> U/V stay resident)
__global__ void __launch_bounds__(256, 4)
edge_logit_sorted(const bf16* __restrict__ U, const bf16* __restrict__ V,
                  const int* __restrict__ perm, const u16* __restrict__ srcS,
                  const u16* __restrict__ dstS,
                  const bf16* __restrict__ W2eroT, const bf16* __restrict__ W2lgT,
                  const float* __restrict__ b2ero, const float* __restrict__ b2lg,
                  float* __restrict__ e_ro, float* __restrict__ e_lg) {
    __shared__ int s_e[128];
    __shared__ int s_s[128];
    __shared__ int s_d[128];
    const int t = threadIdx.x, wv = t >> 6, l = t & 63, lr = l & 15, qk = l >> 4;
    const int bid = (int)blockIdx.x;
    const int cpx = (int)(gridDim.x >> 3);
    const int sbid = (bid & 7) * cpx + (bid >> 3);
    const int p0 = sbid * 128;
    if (t < 128) {
        int p = min(p0 + t, NE - 1);
        s_e[t] = perm[p];
        s_s[t] = (int)srcS[p];
        s_d[t] = (int)dstS[p];
    }
    __syncthreads();

    int is[2], id[2];
#pragma unroll
    for (int m = 0; m < 2; ++m) {
        int el = wv * 32 + m * 16 + lr;
        is[m] = s_s[el];
        id[m] = s_d[el];
    }
    f32x4 aro[2][8];
    f32x4 alg[2];
#pragma unroll
    for (int m = 0; m < 2; ++m) {
        alg[m] = 0.f;
#pragma unroll
        for (int n = 0; n < 8; ++n) aro[m][n] = 0.f;
    }
#pragma unroll
    for (int ks = 0; ks < 8; ++ks) {
        const int kg = ks * 32 + qk * 8;
        bf16x8 a[2];
#pragma unroll
        for (int m = 0; m < 2; ++m) {
            bf16x8 us = ld8(U + (size_t)is[m] * 256 + kg);
            bf16x8 vd = ld8(V + (size_t)id[m] * 256 + kg);
            bf16x8 ud = ld8(U + (size_t)id[m] * 256 + kg);
            bf16x8 vs = ld8(V + (size_t)is[m] * 256 + kg);
#pragma unroll
            for (int i = 0; i < 8; ++i) {
                float f1 = (float)us[i] + (float)vd[i]; f1 = f1 > 0.f ? f1 : 0.f;
                float f2 = (float)ud[i] + (float)vs[i]; f2 = f2 > 0.f ? f2 : 0.f;
                a[m][i] = (bf16)(f1 + f2);
            }
        }
#pragma unroll
        for (int n = 0; n < 8; ++n) {
            bf16x8 b = ld8(W2eroT + (n * 16 + lr) * 256 + kg);
#pragma unroll
            for (int m = 0; m < 2; ++m) aro[m][n] = mfma16(a[m], b, aro[m][n]);
        }
        bf16x8 blg = ld8(W2lgT + lr * 256 + kg);
#pragma unroll
        for (int m = 0; m < 2; ++m) alg[m] = mfma16(a[m], blg, alg[m]);
    }
#pragma unroll
    for (int n = 0; n < 8; ++n) {
        int col = n * 16 + lr;
        float bia = b2ero[col];
#pragma unroll
        for (int m = 0; m < 2; ++m)
#pragma unroll
            for (int j = 0; j < 4; ++j) {
                int el = wv * 32 + m * 16 + qk * 4 + j;
                __builtin_nontemporal_store(aro[m][n][j] + bia,
                                            e_ro + (size_t)s_e[el] * D + col);
            }
    }
    if (lr < 2) {
        float bia = b2lg[lr];
#pragma unroll
        for (int m = 0; m < 2; ++m)
#pragma unroll
            for (int j = 0; j < 4; ++j) {
                int el = wv * 32 + m * 16 + qk * 4 + j;
                e_lg[(size_t)s_e[el] * 2 + lr] = alg[m][j] + bia;
            }
    }
}

// ---------------------------------------------------------------- fallback kernels (round-2 path)
__global__ void __launch_bounds__(256, 4)
edge_msg_kernel(const bf16* __restrict__ S, const bf16* __restrict__ Bm,
                const int* __restrict__ src, const int* __restrict__ dst,
                const bf16* __restrict__ We2T,
                const float* __restrict__ b_e2,
                float* __restrict__ h_out) {
    __shared__ int s_src[128];
    __shared__ int s_dst[128];
    const int t = threadIdx.x, wv = t >> 6, l = t & 63, lr = l & 15, qk = l >> 4;
    const int e0 = blockIdx.x * 128;
    if (t < 128)      s_src[t] = src[min(e0 + t, NE - 1)];
    else              s_dst[t - 128] = dst[min(e0 + t - 128, NE - 1)];
    __syncthreads();
    const bf16* pS[2];
    const bf16* pB[2];
#pragma unroll
    for (int m = 0; m < 2; ++m) {
        int el = wv * 32 + m * 16 + lr;
        pS[m] = S + s_src[el] * 256;
        pB[m] = Bm + s_dst[el] * 256;
    }
    f32x4 acc[2][8];
#pragma unroll
    for (int m = 0; m < 2; ++m)
#pragma unroll
        for (int n = 0; n < 8; ++n) acc[m][n] = 0.f;
#pragma unroll
    for (int ks = 0; ks < 8; ++ks) {
        const int kg = ks * 32 + qk * 8;
        bf16x8 a[2];
#pragma unroll
        for (int m = 0; m < 2; ++m) {
            bf16x8 sa = ld8(pS[m] + kg);
            bf16x8 sb = ld8(pB[m] + kg);
#pragma unroll
            for (int i = 0; i < 8; ++i) {
                float f = (float)sa[i] + (float)sb[i];
                a[m][i] = (bf16)(f > 0.f ? f : 0.f);
            }
        }
#pragma unroll
        for (int n = 0; n < 8; ++n) {
            bf16x8 b = ld8(We2T + (n * 16 + lr) * 256 + kg);
#pragma unroll
            for (int m = 0; m < 2; ++m) acc[m][n] = mfma16(a[m], b, acc[m][n]);
        }
    }
#pragma unroll
    for (int n = 0; n < 8; ++n) {
        int col = n * 16 + lr;
        float bia = b_e2[col];
#pragma unroll
        for (int m = 0; m < 2; ++m)
#pragma unroll
            for (int j = 0; j < 4; ++j) {
                int el = wv * 32 + m * 16 + qk * 4 + j;
                if (e0 + el < NE)
                    atomicAdd(h_out + s_dst[el] * D + col, acc[m][n][j] + bia);
            }
    }
}

__global__ void __launch_bounds__(256, 4)
edge_logit_fast(const bf16* __restrict__ U, const bf16* __restrict__ V,
                const int* __restrict__ src, const int* __restrict__ dst,
                const bf16* __restrict__ W2eroT,
                const bf16* __restrict__ W2lgT,
                const float* __restrict__ b2ero, const float* __restrict__ b2lg,
                float* __restrict__ e_ro, float* __restrict__ e_lg) {
    __shared__ int s_src[128];
    __shared__ int s_dst[128];
    const int t = threadIdx.x, wv = t >> 6, l = t & 63, lr = l & 15, qk = l >> 4;
    const int e0 = blockIdx.x * 128;
    if (t < 128)      s_src[t] = src[min(e0 + t, NE - 1)];
    else              s_dst[t - 128] = dst[min(e0 + t - 128, NE - 1)];
    __syncthreads();
    int is[2], id[2];
#pragma unroll
    for (int m = 0; m < 2; ++m) {
        int el = wv * 32 + m * 16 + lr;
        is[m] = s_src[el];
        id[m] = s_dst[el];
    }
    f32x4 aro[2][8];
    f32x4 alg[2];
#pragma unroll
    for (int m = 0; m < 2; ++m) {
        alg[m] = 0.f;
#pragma unroll
        for (int n = 0; n < 8; ++n) aro[m][n] = 0.f;
    }
#pragma unroll
    for (int ks = 0; ks < 8; ++ks) {
        const int kg = ks * 32 + qk * 8;
        bf16x8 a[2];
#pragma unroll
        for (int m = 0; m < 2; ++m) {
            bf16x8 us = ld8(U + is[m] * 256 + kg);
            bf16x8 vd = ld8(V + id[m] * 256 + kg);
            bf16x8 ud = ld8(U + id[m] * 256 + kg);
            bf16x8 vs = ld8(V + is[m] * 256 + kg);
#pragma unroll
            for (int i = 0; i < 8; ++i) {
                float f1 = (float)us[i] + (float)vd[i]; f1 = f1 > 0.f ? f1 : 0.f;
                float f2 = (float)ud[i] + (float)vs[i]; f2 = f2 > 0.f ? f2 : 0.f;
                a[m][i] = (bf16)(f1 + f2);
            }
        }
#pragma unroll
        for (int n = 0; n < 8; ++n) {
            bf16x8 b = ld8(W2eroT + (n * 16 + lr) * 256 + kg);
#pragma unroll
            for (int m = 0; m < 2; ++m) aro[m][n] = mfma16(a[m], b, aro[m][n]);
        }
        bf16x8 blg = ld8(W2lgT + lr * 256 + kg);
#pragma unroll
        for (int m = 0; m < 2; ++m) alg[m] = mfma16(a[m], blg, alg[m]);
    }
#pragma unroll
    for (int n = 0; n < 8; ++n) {
        int col = n * 16 + lr;
        float bia = b2ero[col];
#pragma unroll
        for (int m = 0; m < 2; ++m)
#pragma unroll
            for (int j = 0; j < 4; ++j) {
                int el = wv * 32 + m * 16 + qk * 4 + j;
                int e = e0 + el;
                if (e < NE) e_ro[e * D + col] = aro[m][n][j] + bia;
            }
    }
    if (lr < 2) {
        float bia = b2lg[lr];
#pragma unroll
        for (int m = 0; m < 2; ++m)
#pragma unroll
            for (int j = 0; j < 4; ++j) {
                int el = wv * 32 + m * 16 + qk * 4 + j;
                int e = e0 + el;
                if (e < NE) e_lg[e * 2 + lr] = alg[m][j] + bia;
            }
    }
}

// ---------------------------------------------------------------- n_out readout
__global__ void __launch_bounds__(256, 4)
nro_kernel(const bf16* __restrict__ nf2_bf, const bf16* __restrict__ WnroT,
           const float* __restrict__ b_nro, float* __restrict__ n_out) {
    const int r0 = blockIdx.x * 64;
    const int t = threadIdx.x, wv = t >> 6, l = t & 63, lr = l & 15, qk = l >> 4;
    int row[4];
#pragma unroll
    for (int m = 0; m < 4; ++m) { int r = r0 + m * 16 + lr; row[m] = r < NN ? r : NN - 1; }
    int col2[2];
#pragma unroll
    for (int n = 0; n < 2; ++n) col2[n] = wv * 32 + n * 16 + lr;
    f32x4 acc[4][2];
#pragma unroll
    for (int m = 0; m < 4; ++m)
#pragma unroll
        for (int n = 0; n < 2; ++n) acc[m][n] = 0.f;
#pragma unroll
    for (int ks = 0; ks < 4; ++ks) {
        const int kg = ks * 32 + qk * 8;
        bf16x8 a[4], b[2];
#pragma unroll
        for (int m = 0; m < 4; ++m) a[m] = ld8(nf2_bf + (size_t)row[m] * D + kg);
#pragma unroll
        for (int n = 0; n < 2; ++n) b[n] = ld8(WnroT + col2[n] * 128 + kg);
#pragma unroll
        for (int m = 0; m < 4; ++m)
#pragma unroll
            for (int n = 0; n < 2; ++n) acc[m][n] = mfma16(a[m], b[n], acc[m][n]);
    }
#pragma unroll
    for (int n = 0; n < 2; ++n) {
        float bia = b_nro[col2[n]];
#pragma unroll
        for (int m = 0; m < 4; ++m)
#pragma unroll
            for (int j = 0; j < 4; ++j) {
                int gr = r0 + m * 16 + qk * 4 + j;
                if (gr < NN) n_out[(size_t)gr * D + col2[n]] = acc[m][n][j] + bia;
            }
    }
}

// ---------------------------------------------------------------- launch
extern "C" void kernel_launch(void* const* d_in, const int* in_sizes, int n_in,
                              void* d_out, int out_size, void* d_ws, size_t ws_size,
                              hipStream_t stream) {
    const float* node_feat = (const float*)d_in[0];
    const int*   src   = (const int*)d_in[1];
    const int*   dst   = (const int*)d_in[2];
    const float* W_e1  = (const float*)d_in[3];
    const float* b_e1  = (const float*)d_in[4];
    const float* W_e2  = (const float*)d_in[5];
    const float* b_e2  = (const float*)d_in[6];
    const float* W_n1  = (const float*)d_in[7];
    const float* b_n1  = (const float*)d_in[8];
    const float* W_n2  = (const float*)d_in[9];
    const float* b_n2  = (const float*)d_in[10];
    const float* W_el1 = (const float*)d_in[11];
    const float* b_el1 = (const float*)d_in[12];
    const float* W_el2 = (const float*)d_in[13];
    const float* b_el2 = (const float*)d_in[14];
    const float* W_logit = (const float*)d_in[15];
    const float* b_logit = (const float*)d_in[16];
    const float* W_nro = (const float*)d_in[17];
    const float* b_nro = (const float*)d_in[18];
    const float* W_ero = (const float*)d_in[19];
    const float* b_ero = (const float*)d_in[20];

    char* ws = (char*)d_ws;
    bf16* wb = (bf16*)ws;
    bf16* WmbT   = wb;            // [512][128]
    bf16* WtopT  = wb + 65536;    // [256][128]
    bf16* We2T   = wb + 98304;    // [128][256]
    bf16* Wn1T   = wb + 131072;   // [256][256]
    bf16* Wn2T   = wb + 196608;   // [128][256]
    bf16* WuvT   = wb + 229376;   // [512][128]
    bf16* WnroT  = wb + 294912;   // [128][128]
    bf16* W2eroT = wb + 311296;   // [128][256]
    bf16* W2lgT  = wb + 344064;   // [16][256]
    bf16* WcsT   = wb + 348160;   // [256][256]
    bf16* WcnT   = wb + 413696;   // [256][256]  end = 479232 bf16 = 958464 B
    float* fb    = (float*)(ws + 960000);
    float* b2ero = fb;            // 128
    float* b2lg  = fb + 128;      // 2
    float* bcs   = fb + 256;      // 256
    float* bcn   = fb + 512;      // 256

    float* out   = (float*)d_out;
    float* n_out = out;                 // NN*128 f32 (15.36 MB)
    float* e_ro  = out + 3840000;       // NE*128 f32 (307.2 MB)
    float* e_lg  = out + 80640000;      // NE*2 f32 (4.8 MB)

    TPack pk;
    pk.m[0]  = {W_e1 + 128 * 256, WmbT,              128, 256};
    pk.m[1]  = {W_e1 + 256 * 256, WmbT + 256 * 128,  128, 256};
    pk.m[2]  = {W_e1,             WtopT,             128, 256};
    pk.m[3]  = {W_e2,             We2T,              256, 128};
    pk.m[4]  = {W_n1,             Wn1T,              256, 256};
    pk.m[5]  = {W_n2,             Wn2T,              256, 128};
    pk.m[6]  = {W_el1,            WuvT,              128, 256};
    pk.m[7]  = {W_el1 + 128 * 256, WuvT + 256 * 128, 128, 256};
    pk.m[8]  = {W_nro,            WnroT,             128, 128};
    pk.m[9]  = {W_nro,            WnroT,             128, 128};
    pk.m[10] = {W_nro,            WnroT,             128, 128};
    pk.m[11] = {W_nro,            WnroT,             128, 128};

    const size_t NEED_NEW = 28888576;

    if (ws_size >= NEED_NEW) {
        // ---------------- dst-sorted CSR, atomic-free, fused-h ----------------
        char* eb = (char*)e_ro;   // 307.2 MB dead-until-logit space
        bf16* S    = (bf16*)(eb);
        bf16* Bm   = (bf16*)(eb + 15360000);
        bf16* T    = (bf16*)(eb + 30720000);
        int* counts  = (int*)(eb + 61440000);
        int* offsets = (int*)(eb + 61560000);
        int* cursor  = (int*)(eb + 61680004);
        bf16* U    = (bf16*)n_out;           // dead until nro (runs last)
        bf16* nf2_bf = (bf16*)(ws + 1048576);
        bf16* Vbuf   = (bf16*)(ws + 8728576);
        int*  perm   = (int*)(ws + 24088576);
        u16*  srcS   = (u16*)(ws + 26488576);
        u16*  dstS   = (u16*)(ws + 27688576);

        transpose_cast_kernel<<<dim3(12, 40), 256, 0, stream>>>(pk);
        fuse_kernel<<<257, 160, 0, stream>>>(W_el2, W_ero, W_logit, b_el2, b_ero, b_logit,
                                             W2eroT, W2lgT, b2ero, b2lg);
        fuse2_kernel<<<257, 256, 0, stream>>>(W_e2, W_e1, W_n1, b_e2,
                                              WcsT, WcnT, bcs, bcn);
        hipMemsetAsync(counts, 0, NN * 4, stream);
        hist_kernel<<<(NE + 255) / 256, 256, 0, stream>>>(dst, counts);
        scan_kernel<<<1, 1024, 0, stream>>>(counts, offsets, cursor);
        scatter_kernel<<<(NE + 255) / 256, 256, 0, stream>>>(src, dst, cursor,
                                                             perm, srcS, dstS);
        node_pre_kernel<false><<<dim3(469, 2), 256, 0, stream>>>(
            node_feat, nullptr, WmbT, b_e1, S, Bm);
        seg_sum_kernel<<<7500, 256, 0, stream>>>(S, Bm, offsets, srcS, T);
        s2_fused_kernel<<<469, 256, 0, stream>>>(T, WcsT, bcs, counts, S);
        seg_sum_kernel<<<7500, 256, 0, stream>>>(S, Bm, offsets, srcS, T);
        node_mlp_fused<<<469, 256, 0, stream>>>(
            node_feat, T, Wn1T, WcnT, Wn2T, b_n1, bcn, counts, b_n2, nf2_bf);
        node_pre_kernel<true><<<dim3(469, 2), 256, 0, stream>>>(
            nullptr, nf2_bf, WuvT, b_el1, U, Vbuf);
        edge_logit_sorted<<<4688, 256, 0, stream>>>(
            U, Vbuf, perm, srcS, dstS, W2eroT, W2lgT, b2ero, b2lg, e_ro, e_lg);
        nro_kernel<<<469, 256, 0, stream>>>(nf2_bf, WnroT, b_nro, n_out);
    } else {
        // ---------------- fallback: round-2 proven path ----------------
        bf16* nf2_bf = (bf16*)(ws + 1048576);
        bf16* Vbuf   = (bf16*)(ws + 9000000);
        float* h1f = n_out;
        bf16*  S   = (bf16*)e_ro;
        bf16*  Bm  = (bf16*)((char*)e_ro + 15360000);
        float* h2f = (float*)((char*)e_ro + 30720000);
        bf16*  U   = (bf16*)n_out;

        transpose_cast_kernel<<<dim3(12, 40), 256, 0, stream>>>(pk);
        fuse_kernel<<<257, 160, 0, stream>>>(W_el2, W_ero, W_logit, b_el2, b_ero, b_logit,
                                             W2eroT, W2lgT, b2ero, b2lg);
        hipMemsetAsync(h1f, 0, (size_t)NN * D * 4, stream);
        hipMemsetAsync(h2f, 0, (size_t)NN * D * 4, stream);
        node_pre_kernel<false><<<dim3(469, 2), 256, 0, stream>>>(
            node_feat, nullptr, WmbT, b_e1, S, Bm);
        edge_msg_kernel<<<4688, 256, 0, stream>>>(S, Bm, src, dst, We2T, b_e2, h1f);
        s2_update_kernel<<<469, 256, 0, stream>>>(h1f, WtopT, S);
        edge_msg_kernel<<<4688, 256, 0, stream>>>(S, Bm, src, dst, We2T, b_e2, h2f);
        node_mlp_kernel<<<469, 256, 0, stream>>>(
            node_feat, h2f, Wn1T, Wn2T, b_n1, b_n2, nf2_bf);
        node_pre_kernel<true><<<dim3(469, 2), 256, 0, stream>>>(
            nullptr, nf2_bf, WuvT, b_el1, U, Vbuf);
        edge_logit_fast<<<4688, 256, 0, stream>>>(
            U, Vbuf, src, dst, W2eroT, W2lgT, b2ero, b2lg, e_ro, e_lg);
        nro_kernel<<<469, 256, 0, stream>>>(nf2_bf, WnroT, b_nro, n_out);
    }
}